// Round 1
// baseline (2936.474 us; speedup 1.0000x reference)
//
#include <hip/hip_runtime.h>

#define NN 50000
#define NE 800000

// ---------------------------------------------------------------------------
// transform: Y[N,64] = relu(X[N,128] @ W[128,64] + b[64])
// block = 256 threads, 16 rows/block; thread = (c = tid&63, rg = tid>>6) owns
// 4 rows x 1 col. X tile staged in LDS (broadcast reads), W from L1.
// ---------------------------------------------------------------------------
__global__ __launch_bounds__(256) void trans_kernel(
    const float* __restrict__ X, const float* __restrict__ W,
    const float* __restrict__ b, float* __restrict__ Y) {
  __shared__ float Xs[16][128];
  const int row0 = blockIdx.x * 16;
  const int tid = threadIdx.x;
  {
    const float4* Xg = (const float4*)(X + row0 * 128);
    float4* Xl = (float4*)(&Xs[0][0]);
    Xl[tid] = Xg[tid];
    Xl[tid + 256] = Xg[tid + 256];
  }
  __syncthreads();
  const int c = tid & 63;
  const int rg = tid >> 6;
  float acc0 = 0.f, acc1 = 0.f, acc2 = 0.f, acc3 = 0.f;
#pragma unroll 4
  for (int k = 0; k < 128; ++k) {
    const float wv = W[k * 64 + c];
    acc0 += Xs[rg * 4 + 0][k] * wv;
    acc1 += Xs[rg * 4 + 1][k] * wv;
    acc2 += Xs[rg * 4 + 2][k] * wv;
    acc3 += Xs[rg * 4 + 3][k] * wv;
  }
  const float bv = b[c];
  const int base = (row0 + rg * 4) * 64 + c;
  Y[base + 0]   = fmaxf(acc0 + bv, 0.f);
  Y[base + 64]  = fmaxf(acc1 + bv, 0.f);
  Y[base + 128] = fmaxf(acc2 + bv, 0.f);
  Y[base + 192] = fmaxf(acc3 + bv, 0.f);
}

// ---------------------------------------------------------------------------
// degree counts (float accumulators; exact up to 2^24)
// ---------------------------------------------------------------------------
__global__ __launch_bounds__(256) void count_kernel(
    const int* __restrict__ src, const int* __restrict__ dst,
    float* __restrict__ cnt_dst, float* __restrict__ cnt_src) {
  const int e = blockIdx.x * 256 + threadIdx.x;
  if (e >= NE) return;
  atomicAdd(&cnt_dst[dst[e]], 1.f);
  atomicAdd(&cnt_src[src[e]], 1.f);
}

// ---------------------------------------------------------------------------
// scatter-add: AGG[i] += Y[j] over edges. 16 threads per edge (4 cols each).
// ---------------------------------------------------------------------------
__global__ __launch_bounds__(256) void scatter_kernel(
    const float4* __restrict__ Y4, const int* __restrict__ jidx,
    const int* __restrict__ iidx, float* __restrict__ AGG) {
  const int t = blockIdx.x * 256 + threadIdx.x;
  const int e = t >> 4;
  if (e >= NE) return;
  const int q = t & 15;
  const int j = jidx[e];
  const int i = iidx[e];
  const float4 y = Y4[j * 16 + q];
  float* a = AGG + i * 64 + q * 4;
  atomicAdd(a + 0, y.x);
  atomicAdd(a + 1, y.y);
  atomicAdd(a + 2, y.z);
  atomicAdd(a + 3, y.w);
}

// ---------------------------------------------------------------------------
// update: out[:, colbase..colbase+64) = relu(concat[X, AGG/cnt] @ U[192,64])
// If dup != 0, also write the same 64 values at cols 64..128 (h = [x_u, x_u]).
// X staged to LDS first -> safe when X == out (row-wise dependence only).
// ---------------------------------------------------------------------------
__global__ __launch_bounds__(256) void update_kernel(
    const float* __restrict__ X, const float* __restrict__ AGG,
    const float* __restrict__ cnt, const float* __restrict__ U,
    float* __restrict__ out, const int colbase, const int dup) {
  __shared__ float Xs[16][128];
  __shared__ float As[16][64];
  const int row0 = blockIdx.x * 16;
  const int tid = threadIdx.x;
  {
    const float4* Xg = (const float4*)(X + row0 * 128);
    float4* Xl = (float4*)(&Xs[0][0]);
    Xl[tid] = Xg[tid];
    Xl[tid + 256] = Xg[tid + 256];
    const int r = tid >> 4;
    const int qc = (tid & 15) * 4;
    const float s = 1.f / fmaxf(cnt[row0 + r], 1.f);
    const float4 av = *(const float4*)(AGG + (row0 + r) * 64 + qc);
    As[r][qc + 0] = av.x * s;
    As[r][qc + 1] = av.y * s;
    As[r][qc + 2] = av.z * s;
    As[r][qc + 3] = av.w * s;
  }
  __syncthreads();
  const int c = tid & 63;
  const int rg = tid >> 6;
  float acc0 = 0.f, acc1 = 0.f, acc2 = 0.f, acc3 = 0.f;
#pragma unroll 4
  for (int k = 0; k < 128; ++k) {
    const float uv = U[k * 64 + c];
    acc0 += Xs[rg * 4 + 0][k] * uv;
    acc1 += Xs[rg * 4 + 1][k] * uv;
    acc2 += Xs[rg * 4 + 2][k] * uv;
    acc3 += Xs[rg * 4 + 3][k] * uv;
  }
#pragma unroll 4
  for (int k = 0; k < 64; ++k) {
    const float uv = U[(128 + k) * 64 + c];
    acc0 += As[rg * 4 + 0][k] * uv;
    acc1 += As[rg * 4 + 1][k] * uv;
    acc2 += As[rg * 4 + 2][k] * uv;
    acc3 += As[rg * 4 + 3][k] * uv;
  }
  acc0 = fmaxf(acc0, 0.f);
  acc1 = fmaxf(acc1, 0.f);
  acc2 = fmaxf(acc2, 0.f);
  acc3 = fmaxf(acc3, 0.f);
  const int rbase = row0 + rg * 4;
  float* o = out + rbase * 128 + colbase + c;
  o[0 * 128] = acc0;
  o[1 * 128] = acc1;
  o[2 * 128] = acc2;
  o[3 * 128] = acc3;
  if (dup) {
    float* o2 = out + rbase * 128 + 64 + c;
    o2[0 * 128] = acc0;
    o2[1 * 128] = acc1;
    o2[2 * 128] = acc2;
    o2[3 * 128] = acc3;
  }
}

extern "C" void kernel_launch(void* const* d_in, const int* in_sizes, int n_in,
                              void* d_out, int out_size, void* d_ws, size_t ws_size,
                              hipStream_t stream) {
  const float* x    = (const float*)d_in[0];
  const int*   ei   = (const int*)d_in[1];
  const float* W_u1 = (const float*)d_in[2];
  const float* b_u1 = (const float*)d_in[3];
  const float* U_u1 = (const float*)d_in[4];
  const float* W_d1 = (const float*)d_in[5];
  const float* b_d1 = (const float*)d_in[6];
  const float* U_d1 = (const float*)d_in[7];
  const float* W_u2 = (const float*)d_in[8];
  const float* b_u2 = (const float*)d_in[9];
  const float* U_u2 = (const float*)d_in[10];
  const int* src = ei;        // edge_index[0]
  const int* dst = ei + NE;   // edge_index[1]
  float* out = (float*)d_out;

  float* ws = (float*)d_ws;
  float* cnt_dst = ws;                 // [N]
  float* cnt_src = ws + NN;            // [N]
  float* Y       = ws + 2 * NN;        // [N,64]
  float* AGG     = ws + 2 * NN + 64 * NN; // [N,64]

  const int TB = NN / 16;          // 3125 row-tile blocks
  const int SB = (NE * 16) / 256;  // 50000 scatter blocks
  const int CB = (NE + 255) / 256;

  // degree counts (reused by all passes)
  hipMemsetAsync(cnt_dst, 0, 2 * NN * sizeof(float), stream);
  count_kernel<<<CB, 256, 0, stream>>>(src, dst, cnt_dst, cnt_src);

  // ---- layer 1, up branch (src -> dst), writes out[:, 0:64] ----
  trans_kernel<<<TB, 256, 0, stream>>>(x, W_u1, b_u1, Y);
  hipMemsetAsync(AGG, 0, 64 * NN * sizeof(float), stream);
  scatter_kernel<<<SB, 256, 0, stream>>>((const float4*)Y, src, dst, AGG);
  update_kernel<<<TB, 256, 0, stream>>>(x, AGG, cnt_dst, U_u1, out, 0, 0);

  // ---- layer 1, down branch (dst -> src), writes out[:, 64:128] ----
  trans_kernel<<<TB, 256, 0, stream>>>(x, W_d1, b_d1, Y);
  hipMemsetAsync(AGG, 0, 64 * NN * sizeof(float), stream);
  scatter_kernel<<<SB, 256, 0, stream>>>((const float4*)Y, dst, src, AGG);
  update_kernel<<<TB, 256, 0, stream>>>(x, AGG, cnt_src, U_d1, out, 64, 0);

  // ---- rounds 2 and 3: h = concat[x_u, x_u], in-place on out ----
  for (int r = 0; r < 2; ++r) {
    trans_kernel<<<TB, 256, 0, stream>>>(out, W_u2, b_u2, Y);
    hipMemsetAsync(AGG, 0, 64 * NN * sizeof(float), stream);
    scatter_kernel<<<SB, 256, 0, stream>>>((const float4*)Y, src, dst, AGG);
    update_kernel<<<TB, 256, 0, stream>>>(out, AGG, cnt_dst, U_u2, out, 0, 1);
  }
}

// Round 2
// 693.847 us; speedup vs baseline: 4.2322x; 4.2322x over previous
//
#include <hip/hip_runtime.h>

#define NN 50000
#define NE 800000

// ---------------------------------------------------------------------------
// transform: Y[N,64] = relu(X[N,128] @ W[128,64] + b[64])
// ---------------------------------------------------------------------------
__global__ __launch_bounds__(256) void trans_kernel(
    const float* __restrict__ X, const float* __restrict__ W,
    const float* __restrict__ b, float* __restrict__ Y) {
  __shared__ float Xs[16][128];
  const int row0 = blockIdx.x * 16;
  const int tid = threadIdx.x;
  {
    const float4* Xg = (const float4*)(X + row0 * 128);
    float4* Xl = (float4*)(&Xs[0][0]);
    Xl[tid] = Xg[tid];
    Xl[tid + 256] = Xg[tid + 256];
  }
  __syncthreads();
  const int c = tid & 63;
  const int rg = tid >> 6;
  float acc0 = 0.f, acc1 = 0.f, acc2 = 0.f, acc3 = 0.f;
#pragma unroll 4
  for (int k = 0; k < 128; ++k) {
    const float wv = W[k * 64 + c];
    acc0 += Xs[rg * 4 + 0][k] * wv;
    acc1 += Xs[rg * 4 + 1][k] * wv;
    acc2 += Xs[rg * 4 + 2][k] * wv;
    acc3 += Xs[rg * 4 + 3][k] * wv;
  }
  const float bv = b[c];
  const int base = (row0 + rg * 4) * 64 + c;
  Y[base + 0]   = fmaxf(acc0 + bv, 0.f);
  Y[base + 64]  = fmaxf(acc1 + bv, 0.f);
  Y[base + 128] = fmaxf(acc2 + bv, 0.f);
  Y[base + 192] = fmaxf(acc3 + bv, 0.f);
}

// ---------------------------------------------------------------------------
// CSR build step 1: degree counts (int) into rowptr arrays
// ---------------------------------------------------------------------------
__global__ __launch_bounds__(256) void count_kernel(
    const int* __restrict__ src, const int* __restrict__ dst,
    int* __restrict__ rp_dst, int* __restrict__ rp_src) {
  const int e = blockIdx.x * 256 + threadIdx.x;
  if (e >= NE) return;
  atomicAdd(&rp_dst[dst[e]], 1);
  atomicAdd(&rp_src[src[e]], 1);
}

// ---------------------------------------------------------------------------
// CSR build step 2: in-place exclusive prefix scan of counts -> rowptr.
// One 1024-thread block per array (grid = 2).
// ---------------------------------------------------------------------------
#define CHUNK 49  // ceil(50000/1024)
__global__ __launch_bounds__(1024) void scan_kernel(
    int* __restrict__ a0, int* __restrict__ a1) {
  int* a = (blockIdx.x == 0) ? a0 : a1;
  __shared__ int part[1024];
  const int t = threadIdx.x;
  const int beg = t * CHUNK;
  const int end = min(beg + CHUNK, NN);
  int s = 0;
  for (int i = beg; i < end; ++i) s += a[i];
  part[t] = s;
  __syncthreads();
  for (int off = 1; off < 1024; off <<= 1) {
    int add = (t >= off) ? part[t - off] : 0;
    __syncthreads();
    part[t] += add;
    __syncthreads();
  }
  int run = (t == 0) ? 0 : part[t - 1];
  for (int i = beg; i < end; ++i) {
    const int c = a[i];
    a[i] = run;
    run += c;
  }
}

// ---------------------------------------------------------------------------
// CSR build step 3: placement. Uses rowptr itself as cursor; afterwards
// rowptr[i] == end_i (start_i = rowptr[i-1], start_0 = 0).
// ---------------------------------------------------------------------------
__global__ __launch_bounds__(256) void place_kernel(
    const int* __restrict__ src, const int* __restrict__ dst,
    int* __restrict__ rp_dst, int* __restrict__ rp_src,
    int* __restrict__ col_dst, int* __restrict__ col_src) {
  const int e = blockIdx.x * 256 + threadIdx.x;
  if (e >= NE) return;
  const int s = src[e], d = dst[e];
  const int p1 = atomicAdd(&rp_dst[d], 1);
  col_dst[p1] = s;
  const int p2 = atomicAdd(&rp_src[s], 1);
  col_src[p2] = d;
}

// ---------------------------------------------------------------------------
// pull-gather mean: AGG[i] = mean over neighbors j of Y[j].  One wave per
// node, lane = column; coalesced 256B row reads, zero atomics.
// ---------------------------------------------------------------------------
__global__ __launch_bounds__(256) void gather_kernel(
    const float* __restrict__ Y, const int* __restrict__ rowptr,
    const int* __restrict__ col, float* __restrict__ AGG) {
  const int node = blockIdx.x * 4 + (threadIdx.x >> 6);
  const int lane = threadIdx.x & 63;
  if (node >= NN) return;
  const int start = (node == 0) ? 0 : rowptr[node - 1];
  const int end = rowptr[node];
  float acc = 0.f;
  int e = start;
  for (; e + 1 < end; e += 2) {
    const int j0 = col[e];
    const int j1 = col[e + 1];
    acc += Y[j0 * 64 + lane];
    acc += Y[j1 * 64 + lane];
  }
  if (e < end) acc += Y[col[e] * 64 + lane];
  const float inv = 1.f / (float)max(end - start, 1);
  AGG[node * 64 + lane] = acc * inv;
}

// ---------------------------------------------------------------------------
// update: out[:, colbase..+64) = relu(concat[X, AGG] @ U[192,64])
// AGG already mean-normalized. dup => also write cols 64..128.
// ---------------------------------------------------------------------------
__global__ __launch_bounds__(256) void update_kernel(
    const float* __restrict__ X, const float* __restrict__ AGG,
    const float* __restrict__ U, float* __restrict__ out,
    const int colbase, const int dup) {
  __shared__ float Xs[16][128];
  __shared__ float As[16][64];
  const int row0 = blockIdx.x * 16;
  const int tid = threadIdx.x;
  {
    const float4* Xg = (const float4*)(X + row0 * 128);
    float4* Xl = (float4*)(&Xs[0][0]);
    Xl[tid] = Xg[tid];
    Xl[tid + 256] = Xg[tid + 256];
    const float4* Ag = (const float4*)(AGG + row0 * 64);
    float4* Al = (float4*)(&As[0][0]);
    Al[tid] = Ag[tid];
  }
  __syncthreads();
  const int c = tid & 63;
  const int rg = tid >> 6;
  float acc0 = 0.f, acc1 = 0.f, acc2 = 0.f, acc3 = 0.f;
#pragma unroll 4
  for (int k = 0; k < 128; ++k) {
    const float uv = U[k * 64 + c];
    acc0 += Xs[rg * 4 + 0][k] * uv;
    acc1 += Xs[rg * 4 + 1][k] * uv;
    acc2 += Xs[rg * 4 + 2][k] * uv;
    acc3 += Xs[rg * 4 + 3][k] * uv;
  }
#pragma unroll 4
  for (int k = 0; k < 64; ++k) {
    const float uv = U[(128 + k) * 64 + c];
    acc0 += As[rg * 4 + 0][k] * uv;
    acc1 += As[rg * 4 + 1][k] * uv;
    acc2 += As[rg * 4 + 2][k] * uv;
    acc3 += As[rg * 4 + 3][k] * uv;
  }
  acc0 = fmaxf(acc0, 0.f);
  acc1 = fmaxf(acc1, 0.f);
  acc2 = fmaxf(acc2, 0.f);
  acc3 = fmaxf(acc3, 0.f);
  const int rbase = row0 + rg * 4;
  float* o = out + rbase * 128 + colbase + c;
  o[0 * 128] = acc0;
  o[1 * 128] = acc1;
  o[2 * 128] = acc2;
  o[3 * 128] = acc3;
  if (dup) {
    float* o2 = out + rbase * 128 + 64 + c;
    o2[0 * 128] = acc0;
    o2[1 * 128] = acc1;
    o2[2 * 128] = acc2;
    o2[3 * 128] = acc3;
  }
}

extern "C" void kernel_launch(void* const* d_in, const int* in_sizes, int n_in,
                              void* d_out, int out_size, void* d_ws, size_t ws_size,
                              hipStream_t stream) {
  const float* x    = (const float*)d_in[0];
  const int*   ei   = (const int*)d_in[1];
  const float* W_u1 = (const float*)d_in[2];
  const float* b_u1 = (const float*)d_in[3];
  const float* U_u1 = (const float*)d_in[4];
  const float* W_d1 = (const float*)d_in[5];
  const float* b_d1 = (const float*)d_in[6];
  const float* U_d1 = (const float*)d_in[7];
  const float* W_u2 = (const float*)d_in[8];
  const float* b_u2 = (const float*)d_in[9];
  const float* U_u2 = (const float*)d_in[10];
  const int* src = ei;        // edge_index[0]
  const int* dst = ei + NE;   // edge_index[1]
  float* out = (float*)d_out;

  // workspace layout
  char* wsb = (char*)d_ws;
  int* rp_dst  = (int*)wsb;                       wsb += NN * sizeof(int);
  int* rp_src  = (int*)wsb;                       wsb += NN * sizeof(int);
  int* col_dst = (int*)wsb;                       wsb += NE * sizeof(int);
  int* col_src = (int*)wsb;                       wsb += NE * sizeof(int);
  float* Y     = (float*)wsb;                     wsb += NN * 64 * sizeof(float);
  float* AGG   = (float*)wsb;

  const int TB = NN / 16;           // 3125 row-tile blocks
  const int GB = (NN + 3) / 4;      // 12500 gather blocks (4 waves each)
  const int EB = (NE + 255) / 256;  // edge-parallel blocks

  // ---- CSR build (once per call) ----
  hipMemsetAsync(rp_dst, 0, 2 * NN * sizeof(int), stream);
  count_kernel<<<EB, 256, 0, stream>>>(src, dst, rp_dst, rp_src);
  scan_kernel<<<2, 1024, 0, stream>>>(rp_dst, rp_src);
  place_kernel<<<EB, 256, 0, stream>>>(src, dst, rp_dst, rp_src, col_dst, col_src);

  // ---- layer 1, up branch (src -> dst), writes out[:, 0:64] ----
  trans_kernel<<<TB, 256, 0, stream>>>(x, W_u1, b_u1, Y);
  gather_kernel<<<GB, 256, 0, stream>>>(Y, rp_dst, col_dst, AGG);
  update_kernel<<<TB, 256, 0, stream>>>(x, AGG, U_u1, out, 0, 0);

  // ---- layer 1, down branch (dst -> src), writes out[:, 64:128] ----
  trans_kernel<<<TB, 256, 0, stream>>>(x, W_d1, b_d1, Y);
  gather_kernel<<<GB, 256, 0, stream>>>(Y, rp_src, col_src, AGG);
  update_kernel<<<TB, 256, 0, stream>>>(x, AGG, U_d1, out, 64, 0);

  // ---- rounds 2 and 3: h = concat[x_u, x_u], in-place on out ----
  for (int r = 0; r < 2; ++r) {
    trans_kernel<<<TB, 256, 0, stream>>>(out, W_u2, b_u2, Y);
    gather_kernel<<<GB, 256, 0, stream>>>(Y, rp_dst, col_dst, AGG);
    update_kernel<<<TB, 256, 0, stream>>>(out, AGG, U_u2, out, 0, 1);
  }
}

// Round 3
// 565.630 us; speedup vs baseline: 5.1915x; 1.2267x over previous
//
#include <hip/hip_runtime.h>

#define NN 50000
#define NE 800000
#define PB 3125                       // edge blocks (NE/256)
#define TB ((NN + 63) / 64)           // 782 gemm row-tile blocks

// ---------------------------------------------------------------------------
// Generic 64x64-tile GEMM: out[row0+64, colbase+64) = relu([X|AGG] @ W (+b))
// K = 64*kchunks; first xchunks chunks read X (ld=ldx), rest read AGG (ld=64).
// Thread (tx,ty) owns 4 rows x 4 cols. X chunk staged transposed in LDS.
// ---------------------------------------------------------------------------
__device__ __forceinline__ void gemm64_dev(
    float (*Xt)[68], float* Ws,
    const float* __restrict__ X, int ldx, const float* __restrict__ AGG,
    const float* __restrict__ W, const float* __restrict__ b,
    float* __restrict__ out, int ldo, int colbase, int dup,
    int kchunks, int xchunks, int row0, int tid) {
  const int tx = tid & 15, ty = tid >> 4;
  float acc[4][4] = {{0.f}};
  for (int c = 0; c < kchunks; ++c) {
    // ---- stage X chunk (64 rows x 64 k) transposed ----
    {
      const int rr = tid >> 2;
      const int cg = (tid & 3) << 4;
      const float* srcp;
      int ld, co;
      if (c < xchunks) { srcp = X; ld = ldx; co = c * 64; }
      else             { srcp = AGG; ld = 64; co = 0; }
      int row = row0 + rr;
      if (row > NN - 1) row = NN - 1;
      const float* g = srcp + row * ld + co + cg;
      const float4 v0 = *(const float4*)(g + 0);
      const float4 v1 = *(const float4*)(g + 4);
      const float4 v2 = *(const float4*)(g + 8);
      const float4 v3 = *(const float4*)(g + 12);
      Xt[cg + 0][rr] = v0.x;  Xt[cg + 1][rr] = v0.y;
      Xt[cg + 2][rr] = v0.z;  Xt[cg + 3][rr] = v0.w;
      Xt[cg + 4][rr] = v1.x;  Xt[cg + 5][rr] = v1.y;
      Xt[cg + 6][rr] = v1.z;  Xt[cg + 7][rr] = v1.w;
      Xt[cg + 8][rr] = v2.x;  Xt[cg + 9][rr] = v2.y;
      Xt[cg + 10][rr] = v2.z; Xt[cg + 11][rr] = v2.w;
      Xt[cg + 12][rr] = v3.x; Xt[cg + 13][rr] = v3.y;
      Xt[cg + 14][rr] = v3.z; Xt[cg + 15][rr] = v3.w;
      // ---- stage W chunk (64 k x 64 cols), linear copy ----
      const float4* wg = (const float4*)(W + c * 64 * 64);
      float4* wl = (float4*)Ws;
      wl[tid] = wg[tid];
      wl[tid + 256] = wg[tid + 256];
      wl[tid + 512] = wg[tid + 512];
      wl[tid + 768] = wg[tid + 768];
    }
    __syncthreads();
#pragma unroll 8
    for (int kk = 0; kk < 64; ++kk) {
      const float4 a = *(const float4*)&Xt[kk][tx << 2];
      const float4 w = *(const float4*)&Ws[kk * 64 + (ty << 2)];
      acc[0][0] += a.x * w.x; acc[0][1] += a.x * w.y;
      acc[0][2] += a.x * w.z; acc[0][3] += a.x * w.w;
      acc[1][0] += a.y * w.x; acc[1][1] += a.y * w.y;
      acc[1][2] += a.y * w.z; acc[1][3] += a.y * w.w;
      acc[2][0] += a.z * w.x; acc[2][1] += a.z * w.y;
      acc[2][2] += a.z * w.z; acc[2][3] += a.z * w.w;
      acc[3][0] += a.w * w.x; acc[3][1] += a.w * w.y;
      acc[3][2] += a.w * w.z; acc[3][3] += a.w * w.w;
    }
    __syncthreads();
  }
  float4 bv = make_float4(0.f, 0.f, 0.f, 0.f);
  if (b) bv = *(const float4*)(b + (ty << 2));
#pragma unroll
  for (int i = 0; i < 4; ++i) {
    const int row = row0 + (tx << 2) + i;
    if (row < NN) {
      float4 o;
      o.x = fmaxf(acc[i][0] + bv.x, 0.f);
      o.y = fmaxf(acc[i][1] + bv.y, 0.f);
      o.z = fmaxf(acc[i][2] + bv.z, 0.f);
      o.w = fmaxf(acc[i][3] + bv.w, 0.f);
      *(float4*)(out + row * ldo + colbase + (ty << 2)) = o;
      if (dup) *(float4*)(out + row * ldo + 64 + (ty << 2)) = o;
    }
  }
}

__global__ __launch_bounds__(256) void gemm_kernel(
    const float* __restrict__ X, int ldx, const float* __restrict__ AGG,
    const float* __restrict__ W, const float* __restrict__ b,
    float* __restrict__ out, int ldo, int colbase, int dup,
    int kchunks, int xchunks) {
  __shared__ __align__(16) float Xt[64][68];
  __shared__ __align__(16) float Ws[4096];
  gemm64_dev(Xt, Ws, X, ldx, AGG, W, b, out, ldo, colbase, dup,
             kchunks, xchunks, blockIdx.x * 64, threadIdx.x);
}

// ---------------------------------------------------------------------------
// CSR build
// ---------------------------------------------------------------------------
__global__ __launch_bounds__(256) void count_kernel(
    const int* __restrict__ src, const int* __restrict__ dst,
    int* __restrict__ rp_dst, int* __restrict__ rp_src) {
  const int e = blockIdx.x * 256 + threadIdx.x;
  if (e >= NE) return;
  atomicAdd(&rp_dst[dst[e]], 1);
  atomicAdd(&rp_src[src[e]], 1);
}

#define CHUNK 49  // ceil(50000/1024)
__global__ __launch_bounds__(1024) void scan_kernel(
    int* __restrict__ a0, int* __restrict__ a1) {
  int* a = (blockIdx.x == 0) ? a0 : a1;
  __shared__ int part[1024];
  const int t = threadIdx.x;
  const int beg = t * CHUNK;
  const int end = min(beg + CHUNK, NN);
  int s = 0;
  for (int i = beg; i < end; ++i) s += a[i];
  part[t] = s;
  __syncthreads();
  for (int off = 1; off < 1024; off <<= 1) {
    int add = (t >= off) ? part[t - off] : 0;
    __syncthreads();
    part[t] += add;
    __syncthreads();
  }
  int run = (t == 0) ? 0 : part[t - 1];
  for (int i = beg; i < end; ++i) {
    const int c = a[i];
    a[i] = run;
    run += c;
  }
}

__device__ __forceinline__ void place_dev(
    const int* __restrict__ src, const int* __restrict__ dst,
    int* __restrict__ rp_dst, int* __restrict__ rp_src,
    int* __restrict__ col_dst, int* __restrict__ col_src, int e) {
  if (e >= NE) return;
  const int s = src[e], d = dst[e];
  col_dst[atomicAdd(&rp_dst[d], 1)] = s;
  col_src[atomicAdd(&rp_src[s], 1)] = d;
}

__global__ __launch_bounds__(256) void place_kernel(
    const int* __restrict__ src, const int* __restrict__ dst,
    int* __restrict__ rp_dst, int* __restrict__ rp_src,
    int* __restrict__ col_dst, int* __restrict__ col_src) {
  place_dev(src, dst, rp_dst, rp_src, col_dst, col_src,
            blockIdx.x * 256 + threadIdx.x);
}

// ---------------------------------------------------------------------------
// mega: place (blocks [0,PB)) || trans_u1 || trans_d1 in one launch
// ---------------------------------------------------------------------------
__global__ __launch_bounds__(256) void mega_kernel(
    const int* __restrict__ src, const int* __restrict__ dst,
    int* __restrict__ rp_dst, int* __restrict__ rp_src,
    int* __restrict__ col_dst, int* __restrict__ col_src,
    const float* __restrict__ x,
    const float* __restrict__ W_u1, const float* __restrict__ b_u1,
    float* __restrict__ Y_u,
    const float* __restrict__ W_d1, const float* __restrict__ b_d1,
    float* __restrict__ Y_d) {
  __shared__ __align__(16) float Xt[64][68];
  __shared__ __align__(16) float Ws[4096];
  int bi = blockIdx.x;
  if (bi < PB) {
    place_dev(src, dst, rp_dst, rp_src, col_dst, col_src,
              bi * 256 + threadIdx.x);
    return;
  }
  bi -= PB;
  if (bi < TB) {
    gemm64_dev(Xt, Ws, x, 128, nullptr, W_u1, b_u1, Y_u, 64, 0, 0, 2, 2,
               bi * 64, threadIdx.x);
  } else {
    bi -= TB;
    gemm64_dev(Xt, Ws, x, 128, nullptr, W_d1, b_d1, Y_d, 64, 0, 0, 2, 2,
               bi * 64, threadIdx.x);
  }
}

// ---------------------------------------------------------------------------
// pull-gather mean: wave per node, 4 edges x 16 lanes x float4
// ---------------------------------------------------------------------------
__global__ __launch_bounds__(256) void gather_kernel(
    const float* __restrict__ Y, const int* __restrict__ rowptr,
    const int* __restrict__ col, float* __restrict__ AGG) {
  const int node = blockIdx.x * 4 + (threadIdx.x >> 6);
  const int lane = threadIdx.x & 63;
  const int eg = lane >> 4;
  const int cq = (lane & 15) << 2;
  const int start = (node == 0) ? 0 : rowptr[node - 1];
  const int end = rowptr[node];
  float4 acc = make_float4(0.f, 0.f, 0.f, 0.f);
  for (int e = start + eg; e < end; e += 4) {
    const int j = col[e];
    const float4 y = *(const float4*)(Y + j * 64 + cq);
    acc.x += y.x; acc.y += y.y; acc.z += y.z; acc.w += y.w;
  }
  acc.x += __shfl_xor(acc.x, 16);
  acc.y += __shfl_xor(acc.y, 16);
  acc.z += __shfl_xor(acc.z, 16);
  acc.w += __shfl_xor(acc.w, 16);
  acc.x += __shfl_xor(acc.x, 32);
  acc.y += __shfl_xor(acc.y, 32);
  acc.z += __shfl_xor(acc.z, 32);
  acc.w += __shfl_xor(acc.w, 32);
  if (eg == 0) {
    const float inv = 1.f / (float)max(end - start, 1);
    float4 o;
    o.x = acc.x * inv; o.y = acc.y * inv;
    o.z = acc.z * inv; o.w = acc.w * inv;
    *(float4*)(AGG + node * 64 + cq) = o;
  }
}

extern "C" void kernel_launch(void* const* d_in, const int* in_sizes, int n_in,
                              void* d_out, int out_size, void* d_ws, size_t ws_size,
                              hipStream_t stream) {
  const float* x    = (const float*)d_in[0];
  const int*   ei   = (const int*)d_in[1];
  const float* W_u1 = (const float*)d_in[2];
  const float* b_u1 = (const float*)d_in[3];
  const float* U_u1 = (const float*)d_in[4];
  const float* W_d1 = (const float*)d_in[5];
  const float* b_d1 = (const float*)d_in[6];
  const float* U_d1 = (const float*)d_in[7];
  const float* W_u2 = (const float*)d_in[8];
  const float* b_u2 = (const float*)d_in[9];
  const float* U_u2 = (const float*)d_in[10];
  const int* src = ei;
  const int* dst = ei + NE;
  float* out = (float*)d_out;

  char* wsb = (char*)d_ws;
  int* rp_dst  = (int*)wsb;  wsb += NN * sizeof(int);
  int* rp_src  = (int*)wsb;  wsb += NN * sizeof(int);
  int* col_dst = (int*)wsb;  wsb += NE * sizeof(int);
  int* col_src = (int*)wsb;  wsb += NE * sizeof(int);
  float* Y_u   = (float*)wsb; wsb += NN * 64 * sizeof(float);

  const size_t need_fused =
      (size_t)(2 * NN + 2 * NE) * 4 + (size_t)3 * NN * 64 * 4;
  const bool fused = ws_size >= need_fused;

  float* Y_d, *AGG;
  if (fused) {
    Y_d = (float*)wsb; wsb += NN * 64 * sizeof(float);
    AGG = (float*)wsb;
  } else {
    Y_d = Y_u;                 // sequential reuse
    AGG = (float*)wsb;
  }

  const int GB = NN / 4;       // 12500 gather blocks

  hipMemsetAsync(rp_dst, 0, 2 * NN * sizeof(int), stream);
  count_kernel<<<PB, 256, 0, stream>>>(src, dst, rp_dst, rp_src);
  scan_kernel<<<2, 1024, 0, stream>>>(rp_dst, rp_src);

  if (fused) {
    mega_kernel<<<PB + 2 * TB, 256, 0, stream>>>(
        src, dst, rp_dst, rp_src, col_dst, col_src,
        x, W_u1, b_u1, Y_u, W_d1, b_d1, Y_d);
  } else {
    place_kernel<<<PB, 256, 0, stream>>>(src, dst, rp_dst, rp_src,
                                         col_dst, col_src);
    gemm_kernel<<<TB, 256, 0, stream>>>(x, 128, nullptr, W_u1, b_u1,
                                        Y_u, 64, 0, 0, 2, 2);
  }

  // layer 1 up: out[:,0:64]
  gather_kernel<<<GB, 256, 0, stream>>>(Y_u, rp_dst, col_dst, AGG);
  gemm_kernel<<<TB, 256, 0, stream>>>(x, 128, AGG, U_u1, nullptr,
                                      out, 128, 0, 0, 3, 2);
  // layer 1 down: out[:,64:128]
  if (!fused) {
    gemm_kernel<<<TB, 256, 0, stream>>>(x, 128, nullptr, W_d1, b_d1,
                                        Y_d, 64, 0, 0, 2, 2);
  }
  gather_kernel<<<GB, 256, 0, stream>>>(Y_d, rp_src, col_src, AGG);
  gemm_kernel<<<TB, 256, 0, stream>>>(x, 128, AGG, U_d1, nullptr,
                                      out, 128, 64, 0, 3, 2);

  // rounds 2, 3
  for (int r = 0; r < 2; ++r) {
    gemm_kernel<<<TB, 256, 0, stream>>>(out, 128, nullptr, W_u2, b_u2,
                                        Y_u, 64, 0, 0, 2, 2);
    gather_kernel<<<GB, 256, 0, stream>>>(Y_u, rp_dst, col_dst, AGG);
    gemm_kernel<<<TB, 256, 0, stream>>>(out, 128, AGG, U_u2, nullptr,
                                        out, 128, 0, 1, 3, 2);
  }
}

// Round 4
// 456.385 us; speedup vs baseline: 6.4342x; 1.2394x over previous
//
#include <hip/hip_runtime.h>

#define NN 50000
#define NE 800000
#define PB 3125            // NE/256 edge blocks
#define TB 782             // ceil(NN/64) gemm row-tile blocks
#define GB 12500           // NN/4 gather blocks

// ---------------------------------------------------------------------------
// Generic 64x64-tile GEMM: out[row0+64, colbase+64) = relu([X|AGG] @ W (+b))
// K = 64*kchunks; first xchunks chunks read X (ld=ldx), rest read AGG (ld=64).
// Thread (tx,ty) owns 4 rows x 4 cols. X chunk staged transposed in LDS.
// ---------------------------------------------------------------------------
__device__ __forceinline__ void gemm64_dev(
    float (*Xt)[68], float* Ws,
    const float* __restrict__ X, int ldx, const float* __restrict__ AGG,
    const float* __restrict__ W, const float* __restrict__ b,
    float* __restrict__ out, int ldo, int colbase, int dup,
    int kchunks, int xchunks, int row0, int tid) {
  const int tx = tid & 15, ty = tid >> 4;
  float acc[4][4] = {{0.f}};
  for (int c = 0; c < kchunks; ++c) {
    {
      const int rr = tid >> 2;
      const int cg = (tid & 3) << 4;
      const float* srcp;
      int ld, co;
      if (c < xchunks) { srcp = X; ld = ldx; co = c * 64; }
      else             { srcp = AGG; ld = 64; co = 0; }
      int row = row0 + rr;
      if (row > NN - 1) row = NN - 1;
      const float* g = srcp + row * ld + co + cg;
      const float4 v0 = *(const float4*)(g + 0);
      const float4 v1 = *(const float4*)(g + 4);
      const float4 v2 = *(const float4*)(g + 8);
      const float4 v3 = *(const float4*)(g + 12);
      Xt[cg + 0][rr] = v0.x;  Xt[cg + 1][rr] = v0.y;
      Xt[cg + 2][rr] = v0.z;  Xt[cg + 3][rr] = v0.w;
      Xt[cg + 4][rr] = v1.x;  Xt[cg + 5][rr] = v1.y;
      Xt[cg + 6][rr] = v1.z;  Xt[cg + 7][rr] = v1.w;
      Xt[cg + 8][rr] = v2.x;  Xt[cg + 9][rr] = v2.y;
      Xt[cg + 10][rr] = v2.z; Xt[cg + 11][rr] = v2.w;
      Xt[cg + 12][rr] = v3.x; Xt[cg + 13][rr] = v3.y;
      Xt[cg + 14][rr] = v3.z; Xt[cg + 15][rr] = v3.w;
      const float4* wg = (const float4*)(W + c * 64 * 64);
      float4* wl = (float4*)Ws;
      wl[tid] = wg[tid];
      wl[tid + 256] = wg[tid + 256];
      wl[tid + 512] = wg[tid + 512];
      wl[tid + 768] = wg[tid + 768];
    }
    __syncthreads();
#pragma unroll 8
    for (int kk = 0; kk < 64; ++kk) {
      const float4 a = *(const float4*)&Xt[kk][tx << 2];
      const float4 w = *(const float4*)&Ws[kk * 64 + (ty << 2)];
      acc[0][0] += a.x * w.x; acc[0][1] += a.x * w.y;
      acc[0][2] += a.x * w.z; acc[0][3] += a.x * w.w;
      acc[1][0] += a.y * w.x; acc[1][1] += a.y * w.y;
      acc[1][2] += a.y * w.z; acc[1][3] += a.y * w.w;
      acc[2][0] += a.z * w.x; acc[2][1] += a.z * w.y;
      acc[2][2] += a.z * w.z; acc[2][3] += a.z * w.w;
      acc[3][0] += a.w * w.x; acc[3][1] += a.w * w.y;
      acc[3][2] += a.w * w.z; acc[3][3] += a.w * w.w;
    }
    __syncthreads();
  }
  float4 bv = make_float4(0.f, 0.f, 0.f, 0.f);
  if (b) bv = *(const float4*)(b + (ty << 2));
#pragma unroll
  for (int i = 0; i < 4; ++i) {
    const int row = row0 + (tx << 2) + i;
    if (row < NN) {
      float4 o;
      o.x = fmaxf(acc[i][0] + bv.x, 0.f);
      o.y = fmaxf(acc[i][1] + bv.y, 0.f);
      o.z = fmaxf(acc[i][2] + bv.z, 0.f);
      o.w = fmaxf(acc[i][3] + bv.w, 0.f);
      *(float4*)(out + row * ldo + colbase + (ty << 2)) = o;
      if (dup) *(float4*)(out + row * ldo + 64 + (ty << 2)) = o;
    }
  }
}

__global__ __launch_bounds__(256) void gemm_kernel(
    const float* __restrict__ X, int ldx, const float* __restrict__ AGG,
    const float* __restrict__ W, const float* __restrict__ b,
    float* __restrict__ out, int ldo, int colbase, int dup,
    int kchunks, int xchunks) {
  __shared__ __align__(16) float Xt[64][68];
  __shared__ __align__(16) float Ws[4096];
  gemm64_dev(Xt, Ws, X, ldx, AGG, W, b, out, ldo, colbase, dup,
             kchunks, xchunks, blockIdx.x * 64, threadIdx.x);
}

// ---------------------------------------------------------------------------
// fused0: count (blocks [0,PB)) || trans_u1 || trans_d1 || presum (last blk)
// ---------------------------------------------------------------------------
__global__ __launch_bounds__(256) void fused0_kernel(
    const int* __restrict__ src, const int* __restrict__ dst,
    int* __restrict__ rp_dst, int* __restrict__ rp_src,
    const float* __restrict__ x,
    const float* __restrict__ W_u1, const float* __restrict__ b_u1,
    float* __restrict__ Y_u,
    const float* __restrict__ W_d1, const float* __restrict__ b_d1,
    float* __restrict__ Y_d,
    const float* __restrict__ W_u2, const float* __restrict__ U_u2,
    float* __restrict__ Wsum, float* __restrict__ Usum) {
  __shared__ __align__(16) float Xt[64][68];
  __shared__ __align__(16) float Ws[4096];
  int bi = blockIdx.x;
  if (bi < PB) {
    const int e = bi * 256 + threadIdx.x;
    if (e < NE) {
      atomicAdd(&rp_dst[dst[e]], 1);
      atomicAdd(&rp_src[src[e]], 1);
    }
    return;
  }
  bi -= PB;
  if (bi < TB) {
    gemm64_dev(Xt, Ws, x, 128, nullptr, W_u1, b_u1, Y_u, 64, 0, 0, 2, 2,
               bi * 64, threadIdx.x);
    return;
  }
  bi -= TB;
  if (bi < TB) {
    gemm64_dev(Xt, Ws, x, 128, nullptr, W_d1, b_d1, Y_d, 64, 0, 0, 2, 2,
               bi * 64, threadIdx.x);
    return;
  }
  // presum block (only launched in tier A):
  // Wsum[64][64] = W_u2[0:64] + W_u2[64:128]
  // Usum[0:64]   = U_u2[0:64] + U_u2[64:128]; Usum[64:128] = U_u2[128:192]
  const int t = threadIdx.x;
  const float4* W4 = (const float4*)W_u2;
  const float4* U4 = (const float4*)U_u2;
  float4* Ws4 = (float4*)Wsum;
  float4* Us4 = (float4*)Usum;
#pragma unroll
  for (int q = 0; q < 4; ++q) {
    const int i = t * 4 + q;
    const float4 a = W4[i], c = W4[i + 1024];
    Ws4[i] = make_float4(a.x + c.x, a.y + c.y, a.z + c.z, a.w + c.w);
    const float4 ua = U4[i], uc = U4[i + 1024];
    Us4[i] = make_float4(ua.x + uc.x, ua.y + uc.y, ua.z + uc.z, ua.w + uc.w);
    Us4[1024 + i] = U4[2048 + i];
  }
}

// ---------------------------------------------------------------------------
// CSR scan (2 blocks) and XCD-range-partitioned placement
// ---------------------------------------------------------------------------
#define CHUNK 49
__global__ __launch_bounds__(1024) void scan_kernel(
    int* __restrict__ a0, int* __restrict__ a1) {
  int* a = (blockIdx.x == 0) ? a0 : a1;
  __shared__ int part[1024];
  const int t = threadIdx.x;
  const int beg = t * CHUNK;
  const int end = min(beg + CHUNK, NN);
  int s = 0;
  for (int i = beg; i < end; ++i) s += a[i];
  part[t] = s;
  __syncthreads();
  for (int off = 1; off < 1024; off <<= 1) {
    int add = (t >= off) ? part[t - off] : 0;
    __syncthreads();
    part[t] += add;
    __syncthreads();
  }
  int run = (t == 0) ? 0 : part[t - 1];
  for (int i = beg; i < end; ++i) {
    const int c = a[i];
    a[i] = run;
    run += c;
  }
}

// range r = blockIdx&7 -> XCD r (round-robin dispatch). Each XCD writes only
// its own contiguous ~400KB col region -> L2-local dirty accumulation.
__global__ __launch_bounds__(256) void place_part_kernel(
    const int* __restrict__ src, const int* __restrict__ dst,
    int* __restrict__ rp_dst, int* __restrict__ rp_src,
    int* __restrict__ col_dst, int* __restrict__ col_src) {
  const int r = blockIdx.x & 7;
  const int e = (blockIdx.x >> 3) * 256 + threadIdx.x;
  if (e >= NE) return;
  const int s = src[e], d = dst[e];
  const unsigned lo = (unsigned)r * 6250u;
  if ((unsigned)(d - lo) < 6250u)
    col_dst[atomicAdd(&rp_dst[d], 1)] = s;
  if ((unsigned)(s - lo) < 6250u)
    col_src[atomicAdd(&rp_src[s], 1)] = d;
}

// ---------------------------------------------------------------------------
// pull-gather mean, 4x unrolled (4 independent load chains per lane)
// ---------------------------------------------------------------------------
__device__ __forceinline__ void gather_dev(
    const float* __restrict__ Y, const int* __restrict__ rowptr,
    const int* __restrict__ col, float* __restrict__ AGG,
    int node, int lane) {
  const int eg = lane >> 4;
  const int cq = (lane & 15) << 2;
  const int start = (node == 0) ? 0 : rowptr[node - 1];
  const int end = rowptr[node];
  float4 acc = make_float4(0.f, 0.f, 0.f, 0.f);
  int e = start + eg;
  for (; e + 12 < end; e += 16) {
    const int j0 = col[e];
    const int j1 = col[e + 4];
    const int j2 = col[e + 8];
    const int j3 = col[e + 12];
    const float4 y0 = *(const float4*)(Y + j0 * 64 + cq);
    const float4 y1 = *(const float4*)(Y + j1 * 64 + cq);
    const float4 y2 = *(const float4*)(Y + j2 * 64 + cq);
    const float4 y3 = *(const float4*)(Y + j3 * 64 + cq);
    acc.x += y0.x + y1.x + y2.x + y3.x;
    acc.y += y0.y + y1.y + y2.y + y3.y;
    acc.z += y0.z + y1.z + y2.z + y3.z;
    acc.w += y0.w + y1.w + y2.w + y3.w;
  }
  for (; e < end; e += 4) {
    const float4 y = *(const float4*)(Y + col[e] * 64 + cq);
    acc.x += y.x; acc.y += y.y; acc.z += y.z; acc.w += y.w;
  }
  acc.x += __shfl_xor(acc.x, 16);
  acc.y += __shfl_xor(acc.y, 16);
  acc.z += __shfl_xor(acc.z, 16);
  acc.w += __shfl_xor(acc.w, 16);
  acc.x += __shfl_xor(acc.x, 32);
  acc.y += __shfl_xor(acc.y, 32);
  acc.z += __shfl_xor(acc.z, 32);
  acc.w += __shfl_xor(acc.w, 32);
  if (eg == 0) {
    const float inv = 1.f / (float)max(end - start, 1);
    float4 o;
    o.x = acc.x * inv; o.y = acc.y * inv;
    o.z = acc.z * inv; o.w = acc.w * inv;
    *(float4*)(AGG + node * 64 + cq) = o;
  }
}

__global__ __launch_bounds__(256) void gather_kernel(
    const float* __restrict__ Y, const int* __restrict__ rowptr,
    const int* __restrict__ col, float* __restrict__ AGG) {
  gather_dev(Y, rowptr, col, AGG, blockIdx.x * 4 + (threadIdx.x >> 6),
             threadIdx.x & 63);
}

// both directions in one launch
__global__ __launch_bounds__(256) void gather2_kernel(
    const float* __restrict__ Y_u, const int* __restrict__ rp_dst,
    const int* __restrict__ col_dst, float* __restrict__ AGG_u,
    const float* __restrict__ Y_d, const int* __restrict__ rp_src,
    const int* __restrict__ col_src, float* __restrict__ AGG_d) {
  const int lane = threadIdx.x & 63;
  const int w = threadIdx.x >> 6;
  if (blockIdx.x < GB)
    gather_dev(Y_u, rp_dst, col_dst, AGG_u, blockIdx.x * 4 + w, lane);
  else
    gather_dev(Y_d, rp_src, col_src, AGG_d, (blockIdx.x - GB) * 4 + w, lane);
}

// both layer-1 updates in one launch
__global__ __launch_bounds__(256) void update2_kernel(
    const float* __restrict__ x,
    const float* __restrict__ AGG_u, const float* __restrict__ U_u1,
    const float* __restrict__ AGG_d, const float* __restrict__ U_d1,
    float* __restrict__ out) {
  __shared__ __align__(16) float Xt[64][68];
  __shared__ __align__(16) float Ws[4096];
  if (blockIdx.x < TB)
    gemm64_dev(Xt, Ws, x, 128, AGG_u, U_u1, nullptr, out, 128, 0, 0, 3, 2,
               blockIdx.x * 64, threadIdx.x);
  else
    gemm64_dev(Xt, Ws, x, 128, AGG_d, U_d1, nullptr, out, 128, 64, 0, 3, 2,
               (blockIdx.x - TB) * 64, threadIdx.x);
}

extern "C" void kernel_launch(void* const* d_in, const int* in_sizes, int n_in,
                              void* d_out, int out_size, void* d_ws, size_t ws_size,
                              hipStream_t stream) {
  const float* x    = (const float*)d_in[0];
  const int*   ei   = (const int*)d_in[1];
  const float* W_u1 = (const float*)d_in[2];
  const float* b_u1 = (const float*)d_in[3];
  const float* U_u1 = (const float*)d_in[4];
  const float* W_d1 = (const float*)d_in[5];
  const float* b_d1 = (const float*)d_in[6];
  const float* U_d1 = (const float*)d_in[7];
  const float* W_u2 = (const float*)d_in[8];
  const float* b_u2 = (const float*)d_in[9];
  const float* U_u2 = (const float*)d_in[10];
  const int* src = ei;
  const int* dst = ei + NE;
  float* out = (float*)d_out;

  char* wsb = (char*)d_ws;
  int* rp_dst  = (int*)wsb;   wsb += NN * sizeof(int);
  int* rp_src  = (int*)wsb;   wsb += NN * sizeof(int);
  int* col_dst = (int*)wsb;   wsb += NE * sizeof(int);
  int* col_src = (int*)wsb;   wsb += NE * sizeof(int);
  float* Y_u   = (float*)wsb; wsb += (size_t)NN * 64 * sizeof(float);
  float* Y_d   = (float*)wsb; wsb += (size_t)NN * 64 * sizeof(float);
  float* AGG_u = (float*)wsb; wsb += (size_t)NN * 64 * sizeof(float);

  const size_t base = (size_t)(2 * NN + 2 * NE) * 4;
  const size_t big = (size_t)NN * 64 * 4;
  const size_t needA = base + 4 * big + (size_t)(64 * 64 + 128 * 64) * 4;
  const bool tierA = ws_size >= needA;

  hipMemsetAsync(rp_dst, 0, 2 * NN * sizeof(int), stream);

  if (tierA) {
    float* AGG_d = (float*)wsb; wsb += (size_t)NN * 64 * sizeof(float);
    float* Wsum  = (float*)wsb; wsb += (size_t)64 * 64 * sizeof(float);
    float* Usum  = (float*)wsb;
    float* O2 = Y_d;  // round-2 output reuses Y_d (dead after layer 1)

    fused0_kernel<<<PB + 2 * TB + 1, 256, 0, stream>>>(
        src, dst, rp_dst, rp_src, x, W_u1, b_u1, Y_u, W_d1, b_d1, Y_d,
        W_u2, U_u2, Wsum, Usum);
    scan_kernel<<<2, 1024, 0, stream>>>(rp_dst, rp_src);
    place_part_kernel<<<PB * 8, 256, 0, stream>>>(src, dst, rp_dst, rp_src,
                                                  col_dst, col_src);
    // layer 1
    gather2_kernel<<<2 * GB, 256, 0, stream>>>(Y_u, rp_dst, col_dst, AGG_u,
                                               Y_d, rp_src, col_src, AGG_d);
    update2_kernel<<<2 * TB, 256, 0, stream>>>(x, AGG_u, U_u1, AGG_d, U_d1,
                                               out);
    // round 2 (out has distinct halves)
    gemm_kernel<<<TB, 256, 0, stream>>>(out, 128, nullptr, W_u2, b_u2,
                                        Y_u, 64, 0, 0, 2, 2);
    gather_kernel<<<GB, 256, 0, stream>>>(Y_u, rp_dst, col_dst, AGG_u);
    gemm_kernel<<<TB, 256, 0, stream>>>(out, 128, AGG_u, U_u2, nullptr,
                                        O2, 64, 0, 0, 3, 2);
    // round 3 (h = [O2,O2] folded into presummed weights)
    gemm_kernel<<<TB, 256, 0, stream>>>(O2, 64, nullptr, Wsum, b_u2,
                                        Y_u, 64, 0, 0, 1, 1);
    gather_kernel<<<GB, 256, 0, stream>>>(Y_u, rp_dst, col_dst, AGG_u);
    gemm_kernel<<<TB, 256, 0, stream>>>(O2, 64, AGG_u, Usum, nullptr,
                                        out, 128, 0, 1, 2, 1);
  } else {
    // fallback: round-3-equivalent layout (3 big buffers, no presum)
    float* AGG = AGG_u;
    fused0_kernel<<<PB + 2 * TB, 256, 0, stream>>>(
        src, dst, rp_dst, rp_src, x, W_u1, b_u1, Y_u, W_d1, b_d1, Y_d,
        W_u2, U_u2, nullptr, nullptr);
    scan_kernel<<<2, 1024, 0, stream>>>(rp_dst, rp_src);
    place_part_kernel<<<PB * 8, 256, 0, stream>>>(src, dst, rp_dst, rp_src,
                                                  col_dst, col_src);
    gather_kernel<<<GB, 256, 0, stream>>>(Y_u, rp_dst, col_dst, AGG);
    gemm_kernel<<<TB, 256, 0, stream>>>(x, 128, AGG, U_u1, nullptr,
                                        out, 128, 0, 0, 3, 2);
    gather_kernel<<<GB, 256, 0, stream>>>(Y_d, rp_src, col_src, AGG);
    gemm_kernel<<<TB, 256, 0, stream>>>(x, 128, AGG, U_d1, nullptr,
                                        out, 128, 64, 0, 3, 2);
    for (int r = 0; r < 2; ++r) {
      gemm_kernel<<<TB, 256, 0, stream>>>(out, 128, nullptr, W_u2, b_u2,
                                          Y_u, 64, 0, 0, 2, 2);
      gather_kernel<<<GB, 256, 0, stream>>>(Y_u, rp_dst, col_dst, AGG);
      gemm_kernel<<<TB, 256, 0, stream>>>(out, 128, AGG, U_u2, nullptr,
                                          out, 128, 0, 1, 3, 2);
    }
  }
}

// Round 5
// 433.012 us; speedup vs baseline: 6.7815x; 1.0540x over previous
//
#include <hip/hip_runtime.h>

#define NN 50000
#define NE 800000
#define PB 3125            // NE/256 edge blocks
#define TB 782             // ceil(NN/64) gemm row-tile blocks
#define GB 12500           // NN/4 gather blocks

typedef __attribute__((ext_vector_type(8))) short bhalf8;
typedef __attribute__((ext_vector_type(4))) float floatx4;

// weight buffer offsets (ushort units); l plane = h + 64*K
#define WOFF_U1U 0
#define WOFF_U1D 24576
#define WOFF_W1U 49152
#define WOFF_W1D 65536
#define WOFF_W2U 81920
#define WOFF_U2U 98304
#define WOFF_WSUM 122880
#define WOFF_USUM 131072
#define WBUF_USHORTS 147456

// ---------------------------------------------------------------------------
// bf16 split helpers (RNE)
// ---------------------------------------------------------------------------
__device__ __forceinline__ unsigned short bf16hi(float v) {
  union { float f; unsigned u; } c; c.f = v;
  return (unsigned short)((c.u + 0x7FFFu + ((c.u >> 16) & 1u)) >> 16);
}
__device__ __forceinline__ float bf16tof(unsigned short h) {
  union { unsigned u; float f; } c; c.u = ((unsigned)h) << 16;
  return c.f;
}
__device__ __forceinline__ void split1(float v, unsigned short& h,
                                       unsigned short& l) {
  h = bf16hi(v);
  l = bf16hi(v - bf16tof(h));
}
__device__ __forceinline__ void split4(const float4 v, ushort4& h, ushort4& l) {
  split1(v.x, h.x, l.x);
  split1(v.y, h.y, l.y);
  split1(v.z, h.z, l.z);
  split1(v.w, h.w, l.w);
}

// swizzled LDS byte address for bf16 tile [64 rows][64 k] (128B rows)
#define SWZ(row, inrow) (((row) << 7) + ((inrow) ^ (((row)&7) << 4)))

// ---------------------------------------------------------------------------
// MFMA split-bf16 GEMM: out[row0+64, colbase+64) = relu([A|G] @ B^T (+bias))
// A source: hi/lo bf16 row-major (lda); chunks >= xchunks read G (ld=64).
// B source: transposed hi/lo bf16 Wt[64 cols][ldb k].
// 4 waves; wave wm owns 16-row stripe; 4 n-tiles of 16 cols.
// ---------------------------------------------------------------------------
__device__ __forceinline__ void mfma_gemm_dev(
    unsigned short* tAh, unsigned short* tAl,
    unsigned short* tBh, unsigned short* tBl,
    const unsigned short* __restrict__ Ah, const unsigned short* __restrict__ Al,
    int lda,
    const unsigned short* __restrict__ Gh, const unsigned short* __restrict__ Gl,
    const unsigned short* __restrict__ Bh, const unsigned short* __restrict__ Bl,
    int ldb, const float* __restrict__ bias,
    float* __restrict__ outF, unsigned short* __restrict__ outH,
    unsigned short* __restrict__ outL,
    int ldo, int colbase, int dup, int kchunks, int xchunks,
    int row0, int tid) {
  const int lane = tid & 63;
  const int wm = tid >> 6;
  const int m = lane & 15;
  const int kg = lane >> 4;
  floatx4 acc[4];
#pragma unroll
  for (int i = 0; i < 4; ++i) acc[i] = (floatx4){0.f, 0.f, 0.f, 0.f};

  for (int c = 0; c < kchunks; ++c) {
    const unsigned short* sh;
    const unsigned short* sl;
    int ld, kc;
    if (c < xchunks) { sh = Ah; sl = Al; ld = lda; kc = c << 6; }
    else             { sh = Gh; sl = Gl; ld = 64;  kc = 0; }
#pragma unroll
    for (int q = tid; q < 512; q += 256) {
      const int row = q >> 3, slot = q & 7;
      int gr = row0 + row;
      gr = (gr > NN - 1) ? NN - 1 : gr;
      const size_t go = (size_t)gr * ld + kc + slot * 8;
      const uint4 va = *(const uint4*)(sh + go);
      const uint4 vb = *(const uint4*)(sl + go);
      const int ad = SWZ(row, slot << 4);
      *(uint4*)((char*)tAh + ad) = va;
      *(uint4*)((char*)tAl + ad) = vb;
      const size_t gob = (size_t)row * ldb + (c << 6) + slot * 8;
      const uint4 wa = *(const uint4*)(Bh + gob);
      const uint4 wb = *(const uint4*)(Bl + gob);
      *(uint4*)((char*)tBh + ad) = wa;
      *(uint4*)((char*)tBl + ad) = wb;
    }
    __syncthreads();
#pragma unroll
    for (int ks = 0; ks < 2; ++ks) {
      const int inrow = (ks << 6) + (kg << 4);
      const int rA = (wm << 4) + m;
      const bhalf8 ah = *(const bhalf8*)((const char*)tAh + SWZ(rA, inrow));
      const bhalf8 al = *(const bhalf8*)((const char*)tAl + SWZ(rA, inrow));
#pragma unroll
      for (int nt = 0; nt < 4; ++nt) {
        const int rB = (nt << 4) + m;
        const bhalf8 bh = *(const bhalf8*)((const char*)tBh + SWZ(rB, inrow));
        const bhalf8 bl = *(const bhalf8*)((const char*)tBl + SWZ(rB, inrow));
        acc[nt] = __builtin_amdgcn_mfma_f32_16x16x32_bf16(ah, bh, acc[nt], 0, 0, 0);
        acc[nt] = __builtin_amdgcn_mfma_f32_16x16x32_bf16(ah, bl, acc[nt], 0, 0, 0);
        acc[nt] = __builtin_amdgcn_mfma_f32_16x16x32_bf16(al, bh, acc[nt], 0, 0, 0);
      }
    }
    __syncthreads();
  }
#pragma unroll
  for (int nt = 0; nt < 4; ++nt) {
    const int col = colbase + (nt << 4) + m;
    const float bv = bias ? bias[(nt << 4) + m] : 0.f;
#pragma unroll
    for (int r = 0; r < 4; ++r) {
      const int row = row0 + (wm << 4) + (kg << 2) + r;
      if (row < NN) {
        const float v = fmaxf(acc[nt][r] + bv, 0.f);
        if (outF) {
          outF[(size_t)row * ldo + col] = v;
          if (dup) outF[(size_t)row * ldo + col + 64] = v;
        }
        if (outH) {
          unsigned short h, l;
          split1(v, h, l);
          outH[(size_t)row * ldo + col] = h;
          outL[(size_t)row * ldo + col] = l;
        }
      }
    }
  }
}

__global__ __launch_bounds__(256) void mgemm_kernel(
    const unsigned short* Ah, const unsigned short* Al, int lda,
    const unsigned short* Gh, const unsigned short* Gl,
    const unsigned short* Bh, const unsigned short* Bl, int ldb,
    const float* bias, float* outF, unsigned short* outH, unsigned short* outL,
    int ldo, int colbase, int dup, int kchunks, int xchunks) {
  __shared__ unsigned short tiles[4][4096];
  mfma_gemm_dev(tiles[0], tiles[1], tiles[2], tiles[3], Ah, Al, lda, Gh, Gl,
                Bh, Bl, ldb, bias, outF, outH, outL, ldo, colbase, dup,
                kchunks, xchunks, blockIdx.x * 64, threadIdx.x);
}

// both layer-1 updates in one launch (bf16 hi/lo outputs only)
__global__ __launch_bounds__(256) void update2m_kernel(
    const unsigned short* xh, const unsigned short* xl,
    const unsigned short* auh, const unsigned short* aul,
    const unsigned short* adh, const unsigned short* adl,
    const unsigned short* U1uh, const unsigned short* U1ul,
    const unsigned short* U1dh, const unsigned short* U1dl,
    unsigned short* outH, unsigned short* outL) {
  __shared__ unsigned short tiles[4][4096];
  if (blockIdx.x < TB)
    mfma_gemm_dev(tiles[0], tiles[1], tiles[2], tiles[3], xh, xl, 128,
                  auh, aul, U1uh, U1ul, 192, nullptr, nullptr, outH, outL,
                  128, 0, 0, 3, 2, blockIdx.x * 64, threadIdx.x);
  else
    mfma_gemm_dev(tiles[0], tiles[1], tiles[2], tiles[3], xh, xl, 128,
                  adh, adl, U1dh, U1dl, 192, nullptr, nullptr, outH, outL,
                  128, 64, 0, 3, 2, (blockIdx.x - TB) * 64, threadIdx.x);
}

// ---------------------------------------------------------------------------
// prep: count (blocks [0,PB)) || x -> xh/xl (3125 blocks) || weights (1 block)
// ---------------------------------------------------------------------------
__global__ __launch_bounds__(256) void prep_kernel(
    const int* __restrict__ src, const int* __restrict__ dst,
    int* __restrict__ rp_dst, int* __restrict__ rp_src,
    const float* __restrict__ x, unsigned short* __restrict__ xh,
    unsigned short* __restrict__ xl,
    const float* __restrict__ U_u1, const float* __restrict__ U_d1,
    const float* __restrict__ W_u1, const float* __restrict__ W_d1,
    const float* __restrict__ W_u2, const float* __restrict__ U_u2,
    unsigned short* __restrict__ wbuf) {
  int bi = blockIdx.x;
  const int t = threadIdx.x;
  if (bi < PB) {
    const int e = bi * 256 + t;
    if (e < NE) {
      atomicAdd(&rp_dst[dst[e]], 1);
      atomicAdd(&rp_src[src[e]], 1);
    }
    return;
  }
  bi -= PB;
  if (bi < 3125) {
    const int base = (bi * 256 + t) * 8;
    const float4 v0 = *(const float4*)(x + base);
    const float4 v1 = *(const float4*)(x + base + 4);
    ushort4 h0, l0, h1, l1;
    split4(v0, h0, l0);
    split4(v1, h1, l1);
    *(ushort4*)(xh + base) = h0;
    *(ushort4*)(xh + base + 4) = h1;
    *(ushort4*)(xl + base) = l0;
    *(ushort4*)(xl + base + 4) = l1;
    return;
  }
  // weights block: convert + transpose (+presums) into wbuf
  const int Ks[8] = {192, 192, 128, 128, 128, 192, 64, 128};
  const float* srcs[6] = {U_u1, U_d1, W_u1, W_d1, W_u2, U_u2};
  int off = 0;
#pragma unroll
  for (int widx = 0; widx < 8; ++widx) {
    const int K = Ks[widx];
    const int total = K << 6;
    for (int e = t; e < total; e += 256) {
      const int cc = e / K;
      const int kk = e - cc * K;
      float v;
      if (widx < 6) v = srcs[widx][kk * 64 + cc];
      else if (widx == 6) v = W_u2[kk * 64 + cc] + W_u2[(kk + 64) * 64 + cc];
      else v = (kk < 64) ? (U_u2[kk * 64 + cc] + U_u2[(kk + 64) * 64 + cc])
                         : U_u2[(kk + 64) * 64 + cc];
      unsigned short h, l;
      split1(v, h, l);
      wbuf[off + cc * K + kk] = h;
      wbuf[off + (K << 6) + cc * K + kk] = l;
    }
    off += (K << 6) * 2;
  }
}

// ---------------------------------------------------------------------------
// CSR scan (2 blocks)
// ---------------------------------------------------------------------------
#define CHUNK 49
__global__ __launch_bounds__(1024) void scan_kernel(
    int* __restrict__ a0, int* __restrict__ a1) {
  int* a = (blockIdx.x == 0) ? a0 : a1;
  __shared__ int part[1024];
  const int t = threadIdx.x;
  const int beg = t * CHUNK;
  const int end = min(beg + CHUNK, NN);
  int s = 0;
  for (int i = beg; i < end; ++i) s += a[i];
  part[t] = s;
  __syncthreads();
  for (int off = 1; off < 1024; off <<= 1) {
    int add = (t >= off) ? part[t - off] : 0;
    __syncthreads();
    part[t] += add;
    __syncthreads();
  }
  int run = (t == 0) ? 0 : part[t - 1];
  for (int i = beg; i < end; ++i) {
    const int c = a[i];
    a[i] = run;
    run += c;
  }
}

// ---------------------------------------------------------------------------
// fused1: XCD-partitioned place (blocks [0,PB*8)) || trans_u1 || trans_d1
// ---------------------------------------------------------------------------
__global__ __launch_bounds__(256) void fused1_kernel(
    const int* __restrict__ src, const int* __restrict__ dst,
    int* __restrict__ rp_dst, int* __restrict__ rp_src,
    int* __restrict__ col_dst, int* __restrict__ col_src,
    const unsigned short* __restrict__ xh, const unsigned short* __restrict__ xl,
    const unsigned short* W1uh, const unsigned short* W1ul,
    const unsigned short* W1dh, const unsigned short* W1dl,
    const float* __restrict__ b_u1, const float* __restrict__ b_d1,
    float* __restrict__ Yu, float* __restrict__ Yd) {
  __shared__ unsigned short tiles[4][4096];
  int bi = blockIdx.x;
  if (bi < PB * 8) {
    const int r = bi & 7;
    const int e = (bi >> 3) * 256 + threadIdx.x;
    if (e < NE) {
      const int s = src[e], d = dst[e];
      const unsigned lo = (unsigned)r * 6250u;
      if ((unsigned)(d - lo) < 6250u) col_dst[atomicAdd(&rp_dst[d], 1)] = s;
      if ((unsigned)(s - lo) < 6250u) col_src[atomicAdd(&rp_src[s], 1)] = d;
    }
    return;
  }
  bi -= PB * 8;
  if (bi < TB)
    mfma_gemm_dev(tiles[0], tiles[1], tiles[2], tiles[3], xh, xl, 128,
                  nullptr, nullptr, W1uh, W1ul, 128, b_u1, Yu, nullptr,
                  nullptr, 64, 0, 0, 2, 2, bi * 64, threadIdx.x);
  else
    mfma_gemm_dev(tiles[0], tiles[1], tiles[2], tiles[3], xh, xl, 128,
                  nullptr, nullptr, W1dh, W1dl, 128, b_d1, Yd, nullptr,
                  nullptr, 64, 0, 0, 2, 2, (bi - TB) * 64, threadIdx.x);
}

// ---------------------------------------------------------------------------
// pull-gather mean, 4x unrolled; writes f32 (AGGf) or bf16 hi/lo (aggh/aggl)
// ---------------------------------------------------------------------------
__device__ __forceinline__ void gather_dev(
    const float* __restrict__ Y, const int* __restrict__ rowptr,
    const int* __restrict__ col, float* __restrict__ AGGf,
    unsigned short* __restrict__ aggh, unsigned short* __restrict__ aggl,
    int node, int lane) {
  const int eg = lane >> 4;
  const int cq = (lane & 15) << 2;
  const int start = (node == 0) ? 0 : rowptr[node - 1];
  const int end = rowptr[node];
  float4 acc = make_float4(0.f, 0.f, 0.f, 0.f);
  int e = start + eg;
  for (; e + 12 < end; e += 16) {
    const int j0 = col[e];
    const int j1 = col[e + 4];
    const int j2 = col[e + 8];
    const int j3 = col[e + 12];
    const float4 y0 = *(const float4*)(Y + j0 * 64 + cq);
    const float4 y1 = *(const float4*)(Y + j1 * 64 + cq);
    const float4 y2 = *(const float4*)(Y + j2 * 64 + cq);
    const float4 y3 = *(const float4*)(Y + j3 * 64 + cq);
    acc.x += y0.x + y1.x + y2.x + y3.x;
    acc.y += y0.y + y1.y + y2.y + y3.y;
    acc.z += y0.z + y1.z + y2.z + y3.z;
    acc.w += y0.w + y1.w + y2.w + y3.w;
  }
  for (; e < end; e += 4) {
    const float4 y = *(const float4*)(Y + col[e] * 64 + cq);
    acc.x += y.x; acc.y += y.y; acc.z += y.z; acc.w += y.w;
  }
  acc.x += __shfl_xor(acc.x, 16);
  acc.y += __shfl_xor(acc.y, 16);
  acc.z += __shfl_xor(acc.z, 16);
  acc.w += __shfl_xor(acc.w, 16);
  acc.x += __shfl_xor(acc.x, 32);
  acc.y += __shfl_xor(acc.y, 32);
  acc.z += __shfl_xor(acc.z, 32);
  acc.w += __shfl_xor(acc.w, 32);
  if (eg == 0) {
    const float inv = 1.f / (float)max(end - start, 1);
    float4 o;
    o.x = acc.x * inv; o.y = acc.y * inv;
    o.z = acc.z * inv; o.w = acc.w * inv;
    if (AGGf) {
      *(float4*)(AGGf + node * 64 + cq) = o;
    } else {
      ushort4 h, l;
      split4(o, h, l);
      *(ushort4*)(aggh + node * 64 + cq) = h;
      *(ushort4*)(aggl + node * 64 + cq) = l;
    }
  }
}

__global__ __launch_bounds__(256) void gather_kernel(
    const float* __restrict__ Y, const int* __restrict__ rowptr,
    const int* __restrict__ col, float* __restrict__ AGGf,
    unsigned short* __restrict__ aggh, unsigned short* __restrict__ aggl) {
  gather_dev(Y, rowptr, col, AGGf, aggh, aggl,
             blockIdx.x * 4 + (threadIdx.x >> 6), threadIdx.x & 63);
}

__global__ __launch_bounds__(256) void gather2_kernel(
    const float* __restrict__ Yu, const int* __restrict__ rp_dst,
    const int* __restrict__ col_dst, unsigned short* auh, unsigned short* aul,
    const float* __restrict__ Yd, const int* __restrict__ rp_src,
    const int* __restrict__ col_src, unsigned short* adh, unsigned short* adl) {
  const int lane = threadIdx.x & 63;
  const int w = threadIdx.x >> 6;
  if (blockIdx.x < GB)
    gather_dev(Yu, rp_dst, col_dst, nullptr, auh, aul, blockIdx.x * 4 + w, lane);
  else
    gather_dev(Yd, rp_src, col_src, nullptr, adh, adl,
               (blockIdx.x - GB) * 4 + w, lane);
}

// ===========================================================================
// Fallback path (vector-f32 GEMM, round-4 structure) for small workspaces
// ===========================================================================
__device__ __forceinline__ void gemm64_dev(
    float (*Xt)[68], float* Ws, const float* __restrict__ X, int ldx,
    const float* __restrict__ AGG, const float* __restrict__ W,
    const float* __restrict__ b, float* __restrict__ out, int ldo,
    int colbase, int dup, int kchunks, int xchunks, int row0, int tid) {
  const int tx = tid & 15, ty = tid >> 4;
  float acc[4][4] = {{0.f}};
  for (int c = 0; c < kchunks; ++c) {
    {
      const int rr = tid >> 2;
      const int cg = (tid & 3) << 4;
      const float* srcp;
      int ld, co;
      if (c < xchunks) { srcp = X; ld = ldx; co = c * 64; }
      else             { srcp = AGG; ld = 64; co = 0; }
      int row = row0 + rr;
      if (row > NN - 1) row = NN - 1;
      const float* g = srcp + row * ld + co + cg;
      const float4 v0 = *(const float4*)(g + 0);
      const float4 v1 = *(const float4*)(g + 4);
      const float4 v2 = *(const float4*)(g + 8);
      const float4 v3 = *(const float4*)(g + 12);
      Xt[cg + 0][rr] = v0.x;  Xt[cg + 1][rr] = v0.y;
      Xt[cg + 2][rr] = v0.z;  Xt[cg + 3][rr] = v0.w;
      Xt[cg + 4][rr] = v1.x;  Xt[cg + 5][rr] = v1.y;
      Xt[cg + 6][rr] = v1.z;  Xt[cg + 7][rr] = v1.w;
      Xt[cg + 8][rr] = v2.x;  Xt[cg + 9][rr] = v2.y;
      Xt[cg + 10][rr] = v2.z; Xt[cg + 11][rr] = v2.w;
      Xt[cg + 12][rr] = v3.x; Xt[cg + 13][rr] = v3.y;
      Xt[cg + 14][rr] = v3.z; Xt[cg + 15][rr] = v3.w;
      const float4* wg = (const float4*)(W + c * 64 * 64);
      float4* wl = (float4*)Ws;
      wl[tid] = wg[tid];
      wl[tid + 256] = wg[tid + 256];
      wl[tid + 512] = wg[tid + 512];
      wl[tid + 768] = wg[tid + 768];
    }
    __syncthreads();
#pragma unroll 8
    for (int kk = 0; kk < 64; ++kk) {
      const float4 a = *(const float4*)&Xt[kk][tx << 2];
      const float4 w = *(const float4*)&Ws[kk * 64 + (ty << 2)];
      acc[0][0] += a.x * w.x; acc[0][1] += a.x * w.y;
      acc[0][2] += a.x * w.z; acc[0][3] += a.x * w.w;
      acc[1][0] += a.y * w.x; acc[1][1] += a.y * w.y;
      acc[1][2] += a.y * w.z; acc[1][3] += a.y * w.w;
      acc[2][0] += a.z * w.x; acc[2][1] += a.z * w.y;
      acc[2][2] += a.z * w.z; acc[2][3] += a.z * w.w;
      acc[3][0] += a.w * w.x; acc[3][1] += a.w * w.y;
      acc[3][2] += a.w * w.z; acc[3][3] += a.w * w.w;
    }
    __syncthreads();
  }
  float4 bv = make_float4(0.f, 0.f, 0.f, 0.f);
  if (b) bv = *(const float4*)(b + (ty << 2));
#pragma unroll
  for (int i = 0; i < 4; ++i) {
    const int row = row0 + (tx << 2) + i;
    if (row < NN) {
      float4 o;
      o.x = fmaxf(acc[i][0] + bv.x, 0.f);
      o.y = fmaxf(acc[i][1] + bv.y, 0.f);
      o.z = fmaxf(acc[i][2] + bv.z, 0.f);
      o.w = fmaxf(acc[i][3] + bv.w, 0.f);
      *(float4*)(out + row * ldo + colbase + (ty << 2)) = o;
      if (dup) *(float4*)(out + row * ldo + 64 + (ty << 2)) = o;
    }
  }
}

__global__ __launch_bounds__(256) void gemm_kernel(
    const float* __restrict__ X, int ldx, const float* __restrict__ AGG,
    const float* __restrict__ W, const float* __restrict__ b,
    float* __restrict__ out, int ldo, int colbase, int dup,
    int kchunks, int xchunks) {
  __shared__ __align__(16) float Xt[64][68];
  __shared__ __align__(16) float Ws[4096];
  gemm64_dev(Xt, Ws, X, ldx, AGG, W, b, out, ldo, colbase, dup, kchunks,
             xchunks, blockIdx.x * 64, threadIdx.x);
}

__global__ __launch_bounds__(256) void fused0_kernel(
    const int* __restrict__ src, const int* __restrict__ dst,
    int* __restrict__ rp_dst, int* __restrict__ rp_src,
    const float* __restrict__ x,
    const float* __restrict__ W_u1, const float* __restrict__ b_u1,
    float* __restrict__ Y_u,
    const float* __restrict__ W_d1, const float* __restrict__ b_d1,
    float* __restrict__ Y_d) {
  __shared__ __align__(16) float Xt[64][68];
  __shared__ __align__(16) float Ws[4096];
  int bi = blockIdx.x;
  if (bi < PB) {
    const int e = bi * 256 + threadIdx.x;
    if (e < NE) {
      atomicAdd(&rp_dst[dst[e]], 1);
      atomicAdd(&rp_src[src[e]], 1);
    }
    return;
  }
  bi -= PB;
  if (bi < TB)
    gemm64_dev(Xt, Ws, x, 128, nullptr, W_u1, b_u1, Y_u, 64, 0, 0, 2, 2,
               bi * 64, threadIdx.x);
  else
    gemm64_dev(Xt, Ws, x, 128, nullptr, W_d1, b_d1, Y_d, 64, 0, 0, 2, 2,
               (bi - TB) * 64, threadIdx.x);
}

__global__ __launch_bounds__(256) void place_part_kernel(
    const int* __restrict__ src, const int* __restrict__ dst,
    int* __restrict__ rp_dst, int* __restrict__ rp_src,
    int* __restrict__ col_dst, int* __restrict__ col_src) {
  const int r = blockIdx.x & 7;
  const int e = (blockIdx.x >> 3) * 256 + threadIdx.x;
  if (e >= NE) return;
  const int s = src[e], d = dst[e];
  const unsigned lo = (unsigned)r * 6250u;
  if ((unsigned)(d - lo) < 6250u) col_dst[atomicAdd(&rp_dst[d], 1)] = s;
  if ((unsigned)(s - lo) < 6250u) col_src[atomicAdd(&rp_src[s], 1)] = d;
}

// ===========================================================================
extern "C" void kernel_launch(void* const* d_in, const int* in_sizes, int n_in,
                              void* d_out, int out_size, void* d_ws, size_t ws_size,
                              hipStream_t stream) {
  const float* x    = (const float*)d_in[0];
  const int*   ei   = (const int*)d_in[1];
  const float* W_u1 = (const float*)d_in[2];
  const float* b_u1 = (const float*)d_in[3];
  const float* U_u1 = (const float*)d_in[4];
  const float* W_d1 = (const float*)d_in[5];
  const float* b_d1 = (const float*)d_in[6];
  const float* U_d1 = (const float*)d_in[7];
  const float* W_u2 = (const float*)d_in[8];
  const float* b_u2 = (const float*)d_in[9];
  const float* U_u2 = (const float*)d_in[10];
  const int* src = ei;
  const int* dst = ei + NE;
  float* out = (float*)d_out;

  char* wsb = (char*)d_ws;
  int* rp_dst  = (int*)wsb;  wsb += NN * sizeof(int);
  int* rp_src  = (int*)wsb;  wsb += NN * sizeof(int);
  int* col_dst = (int*)wsb;  wsb += NE * sizeof(int);
  int* col_src = (int*)wsb;  wsb += NE * sizeof(int);

  const size_t needM = (size_t)(2 * NN + 2 * NE) * 4 +
                       (size_t)WBUF_USHORTS * 2 +
                       (size_t)NN * 128 * 2 * 2 +   // xh, xl
                       (size_t)NN * 64 * 4 * 2 +    // Yu, Yd
                       (size_t)NN * 64 * 2 * 4;     // 4 agg bf16 planes

  hipMemsetAsync(rp_dst, 0, 2 * NN * sizeof(int), stream);

  if (ws_size >= needM) {
    unsigned short* wbuf = (unsigned short*)wsb; wsb += (size_t)WBUF_USHORTS * 2;
    unsigned short* xh = (unsigned short*)wsb;   wsb += (size_t)NN * 128 * 2;
    unsigned short* xl = (unsigned short*)wsb;   wsb += (size_t)NN * 128 * 2;
    float* Yu = (float*)wsb;                     wsb += (size_t)NN * 64 * 4;
    float* Yd = (float*)wsb;                     wsb += (size_t)NN * 64 * 4;
    unsigned short* agg_uh = (unsigned short*)wsb; wsb += (size_t)NN * 64 * 2;
    unsigned short* agg_ul = (unsigned short*)wsb; wsb += (size_t)NN * 64 * 2;
    unsigned short* agg_dh = (unsigned short*)wsb; wsb += (size_t)NN * 64 * 2;
    unsigned short* agg_dl = (unsigned short*)wsb;

    // aliases (sequential-stream lifetime reuse)
    unsigned short* outh = (unsigned short*)Yu;  // [N][128] bf16 hi
    unsigned short* outl = (unsigned short*)Yd;  // [N][128] bf16 lo
    float* Y2 = (float*)agg_uh;                  // [N][64] f32 (spans uh+ul)
    unsigned short* agg2h = agg_dh;
    unsigned short* agg2l = agg_dl;
    unsigned short* O2h = xh;                    // [N][64] bf16 hi
    unsigned short* O2l = xl;

    const unsigned short* U1uh = wbuf + WOFF_U1U;
    const unsigned short* U1ul = wbuf + WOFF_U1U + 64 * 192;
    const unsigned short* U1dh = wbuf + WOFF_U1D;
    const unsigned short* U1dl = wbuf + WOFF_U1D + 64 * 192;
    const unsigned short* W1uh = wbuf + WOFF_W1U;
    const unsigned short* W1ul = wbuf + WOFF_W1U + 64 * 128;
    const unsigned short* W1dh = wbuf + WOFF_W1D;
    const unsigned short* W1dl = wbuf + WOFF_W1D + 64 * 128;
    const unsigned short* W2uh = wbuf + WOFF_W2U;
    const unsigned short* W2ul = wbuf + WOFF_W2U + 64 * 128;
    const unsigned short* U2uh = wbuf + WOFF_U2U;
    const unsigned short* U2ul = wbuf + WOFF_U2U + 64 * 192;
    const unsigned short* Wsh  = wbuf + WOFF_WSUM;
    const unsigned short* Wsl  = wbuf + WOFF_WSUM + 64 * 64;
    const unsigned short* Ush  = wbuf + WOFF_USUM;
    const unsigned short* Usl  = wbuf + WOFF_USUM + 64 * 128;

    prep_kernel<<<PB + 3125 + 1, 256, 0, stream>>>(
        src, dst, rp_dst, rp_src, x, xh, xl, U_u1, U_d1, W_u1, W_d1, W_u2,
        U_u2, wbuf);
    scan_kernel<<<2, 1024, 0, stream>>>(rp_dst, rp_src);
    fused1_kernel<<<PB * 8 + 2 * TB, 256, 0, stream>>>(
        src, dst, rp_dst, rp_src, col_dst, col_src, xh, xl, W1uh, W1ul,
        W1dh, W1dl, b_u1, b_d1, Yu, Yd);
    // layer 1
    gather2_kernel<<<2 * GB, 256, 0, stream>>>(Yu, rp_dst, col_dst, agg_uh,
                                               agg_ul, Yd, rp_src, col_src,
                                               agg_dh, agg_dl);
    update2m_kernel<<<2 * TB, 256, 0, stream>>>(xh, xl, agg_uh, agg_ul,
                                                agg_dh, agg_dl, U1uh, U1ul,
                                                U1dh, U1dl, outh, outl);
    // round 2
    mgemm_kernel<<<TB, 256, 0, stream>>>(outh, outl, 128, nullptr, nullptr,
                                         W2uh, W2ul, 128, b_u2, Y2, nullptr,
                                         nullptr, 64, 0, 0, 2, 2);
    gather_kernel<<<GB, 256, 0, stream>>>(Y2, rp_dst, col_dst, nullptr,
                                          agg2h, agg2l);
    mgemm_kernel<<<TB, 256, 0, stream>>>(outh, outl, 128, agg2h, agg2l,
                                         U2uh, U2ul, 192, nullptr, nullptr,
                                         O2h, O2l, 64, 0, 0, 3, 2);
    // round 3 (h = [O2,O2] folded into presummed weights)
    mgemm_kernel<<<TB, 256, 0, stream>>>(O2h, O2l, 64, nullptr, nullptr,
                                         Wsh, Wsl, 64, b_u2, Y2, nullptr,
                                         nullptr, 64, 0, 0, 1, 1);
    gather_kernel<<<GB, 256, 0, stream>>>(Y2, rp_dst, col_dst, nullptr,
                                          agg2h, agg2l);
    mgemm_kernel<<<TB, 256, 0, stream>>>(O2h, O2l, 64, agg2h, agg2l,
                                         Ush, Usl, 128, nullptr, out,
                                         nullptr, nullptr, 128, 0, 1, 2, 1);
  } else {
    // fallback: vector-f32 path (round-4 structure)
    float* Y_u = (float*)wsb; wsb += (size_t)NN * 64 * sizeof(float);
    float* Y_d = (float*)wsb; wsb += (size_t)NN * 64 * sizeof(float);
    float* AGG = (float*)wsb;
    fused0_kernel<<<PB + 2 * TB, 256, 0, stream>>>(
        src, dst, rp_dst, rp_src, x, W_u1, b_u1, Y_u, W_d1, b_d1, Y_d);
    scan_kernel<<<2, 1024, 0, stream>>>(rp_dst, rp_src);
    place_part_kernel<<<PB * 8, 256, 0, stream>>>(src, dst, rp_dst, rp_src,
                                                  col_dst, col_src);
    gather_kernel<<<GB, 256, 0, stream>>>(Y_u, rp_dst, col_dst, AGG,
                                          nullptr, nullptr);
    gemm_kernel<<<TB, 256, 0, stream>>>(x, 128, AGG, U_u1, nullptr, out,
                                        128, 0, 0, 3, 2);
    gather_kernel<<<GB, 256, 0, stream>>>(Y_d, rp_src, col_src, AGG,
                                          nullptr, nullptr);
    gemm_kernel<<<TB, 256, 0, stream>>>(x, 128, AGG, U_d1, nullptr, out,
                                        128, 64, 0, 3, 2);
    for (int r = 0; r < 2; ++r) {
      gemm_kernel<<<TB, 256, 0, stream>>>(out, 128, nullptr, W_u2, b_u2,
                                          Y_u, 64, 0, 0, 2, 2);
      gather_kernel<<<GB, 256, 0, stream>>>(Y_u, rp_dst, col_dst, AGG,
                                            nullptr, nullptr);
      gemm_kernel<<<TB, 256, 0, stream>>>(out, 128, AGG, U_u2, nullptr,
                                          out, 128, 0, 1, 3, 2);
    }
  }
}

// Round 6
// 406.442 us; speedup vs baseline: 7.2248x; 1.0654x over previous
//
#include <hip/hip_runtime.h>

#define NN 50000
#define NE 800000
#define PB 3125            // NE/256 edge blocks
#define TB 782             // ceil(NN/64) gemm row-tile blocks
#define GB 12500           // NN/4 gather blocks

typedef __attribute__((ext_vector_type(8))) short bhalf8;
typedef __attribute__((ext_vector_type(4))) float floatx4;

// weight buffer offsets (ushort units); l plane = h + 64*K
#define WOFF_U1U 0
#define WOFF_U1D 24576
#define WOFF_W1U 49152
#define WOFF_W1D 65536
#define WOFF_W2U 81920
#define WOFF_U2U 98304
#define WOFF_WSUM 122880
#define WOFF_USUM 131072
#define WBUF_USHORTS 147456

// ---------------------------------------------------------------------------
// bf16 split helpers (RNE)
// ---------------------------------------------------------------------------
__device__ __forceinline__ unsigned short bf16hi(float v) {
  union { float f; unsigned u; } c; c.f = v;
  return (unsigned short)((c.u + 0x7FFFu + ((c.u >> 16) & 1u)) >> 16);
}
__device__ __forceinline__ float bf16tof(unsigned short h) {
  union { unsigned u; float f; } c; c.u = ((unsigned)h) << 16;
  return c.f;
}
__device__ __forceinline__ void split1(float v, unsigned short& h,
                                       unsigned short& l) {
  h = bf16hi(v);
  l = bf16hi(v - bf16tof(h));
}
__device__ __forceinline__ void split4(const float4 v, ushort4& h, ushort4& l) {
  split1(v.x, h.x, l.x);
  split1(v.y, h.y, l.y);
  split1(v.z, h.z, l.z);
  split1(v.w, h.w, l.w);
}
// 8 floats -> packed hi uint4 + lo uint4 (bf16x2 per uint)
__device__ __forceinline__ void split8(const float4 v0, const float4 v1,
                                       uint4& H, uint4& L) {
  unsigned short h0, l0, h1, l1;
  split1(v0.x, h0, l0); split1(v0.y, h1, l1);
  H.x = (unsigned)h0 | ((unsigned)h1 << 16);
  L.x = (unsigned)l0 | ((unsigned)l1 << 16);
  split1(v0.z, h0, l0); split1(v0.w, h1, l1);
  H.y = (unsigned)h0 | ((unsigned)h1 << 16);
  L.y = (unsigned)l0 | ((unsigned)l1 << 16);
  split1(v1.x, h0, l0); split1(v1.y, h1, l1);
  H.z = (unsigned)h0 | ((unsigned)h1 << 16);
  L.z = (unsigned)l0 | ((unsigned)l1 << 16);
  split1(v1.z, h0, l0); split1(v1.w, h1, l1);
  H.w = (unsigned)h0 | ((unsigned)h1 << 16);
  L.w = (unsigned)l0 | ((unsigned)l1 << 16);
}

// swizzled LDS byte address for bf16 tile [64 rows][64 k] (128B rows)
#define SWZ(row, inrow) (((row) << 7) + ((inrow) ^ (((row)&7) << 4)))

// ---------------------------------------------------------------------------
// MFMA split-bf16 GEMM: out[row0+64, colbase+64) = relu([A|G] @ B^T (+bias))
// AF32: A is f32 row-major, split to hi/lo in-register during staging.
// else: A is hi/lo bf16 planes (Ah/Al). G always hi/lo planes (ld=64).
// B: transposed hi/lo bf16 Wt[64 cols][ldb k].
// ---------------------------------------------------------------------------
template <bool AF32>
__device__ __forceinline__ void mfma_gemm_dev(
    unsigned short* tAh, unsigned short* tAl,
    unsigned short* tBh, unsigned short* tBl,
    const unsigned short* __restrict__ Ah, const unsigned short* __restrict__ Al,
    int lda,
    const unsigned short* __restrict__ Gh, const unsigned short* __restrict__ Gl,
    const unsigned short* __restrict__ Bh, const unsigned short* __restrict__ Bl,
    int ldb, const float* __restrict__ bias,
    float* __restrict__ outF, unsigned short* __restrict__ outH,
    unsigned short* __restrict__ outL,
    int ldo, int colbase, int dup, int kchunks, int xchunks,
    int row0, int tid) {
  const int lane = tid & 63;
  const int wm = tid >> 6;
  const int m = lane & 15;
  const int kg = lane >> 4;
  floatx4 acc[4];
#pragma unroll
  for (int i = 0; i < 4; ++i) acc[i] = (floatx4){0.f, 0.f, 0.f, 0.f};

  for (int c = 0; c < kchunks; ++c) {
#pragma unroll
    for (int q = tid; q < 512; q += 256) {
      const int row = q >> 3, slot = q & 7;
      int gr = row0 + row;
      gr = (gr > NN - 1) ? NN - 1 : gr;
      const int ad = SWZ(row, slot << 4);
      if (AF32 && c < xchunks) {
        const float* f = (const float*)Ah;
        const size_t go = (size_t)gr * lda + (c << 6) + slot * 8;
        const float4 v0 = *(const float4*)(f + go);
        const float4 v1 = *(const float4*)(f + go + 4);
        uint4 H, L;
        split8(v0, v1, H, L);
        *(uint4*)((char*)tAh + ad) = H;
        *(uint4*)((char*)tAl + ad) = L;
      } else {
        const unsigned short* sh;
        const unsigned short* sl;
        int ld, kc;
        if (c < xchunks) { sh = Ah; sl = Al; ld = lda; kc = c << 6; }
        else             { sh = Gh; sl = Gl; ld = 64;  kc = 0; }
        const size_t go = (size_t)gr * ld + kc + slot * 8;
        *(uint4*)((char*)tAh + ad) = *(const uint4*)(sh + go);
        *(uint4*)((char*)tAl + ad) = *(const uint4*)(sl + go);
      }
      const size_t gob = (size_t)row * ldb + (c << 6) + slot * 8;
      *(uint4*)((char*)tBh + ad) = *(const uint4*)(Bh + gob);
      *(uint4*)((char*)tBl + ad) = *(const uint4*)(Bl + gob);
    }
    __syncthreads();
#pragma unroll
    for (int ks = 0; ks < 2; ++ks) {
      const int inrow = (ks << 6) + (kg << 4);
      const int rA = (wm << 4) + m;
      const bhalf8 ah = *(const bhalf8*)((const char*)tAh + SWZ(rA, inrow));
      const bhalf8 al = *(const bhalf8*)((const char*)tAl + SWZ(rA, inrow));
#pragma unroll
      for (int nt = 0; nt < 4; ++nt) {
        const int rB = (nt << 4) + m;
        const bhalf8 bh = *(const bhalf8*)((const char*)tBh + SWZ(rB, inrow));
        const bhalf8 bl = *(const bhalf8*)((const char*)tBl + SWZ(rB, inrow));
        acc[nt] = __builtin_amdgcn_mfma_f32_16x16x32_bf16(ah, bh, acc[nt], 0, 0, 0);
        acc[nt] = __builtin_amdgcn_mfma_f32_16x16x32_bf16(ah, bl, acc[nt], 0, 0, 0);
        acc[nt] = __builtin_amdgcn_mfma_f32_16x16x32_bf16(al, bh, acc[nt], 0, 0, 0);
      }
    }
    __syncthreads();
  }
#pragma unroll
  for (int nt = 0; nt < 4; ++nt) {
    const int col = colbase + (nt << 4) + m;
    const float bv = bias ? bias[(nt << 4) + m] : 0.f;
#pragma unroll
    for (int r = 0; r < 4; ++r) {
      const int row = row0 + (wm << 4) + (kg << 2) + r;
      if (row < NN) {
        const float v = fmaxf(acc[nt][r] + bv, 0.f);
        if (outF) {
          outF[(size_t)row * ldo + col] = v;
          if (dup) outF[(size_t)row * ldo + col + 64] = v;
        }
        if (outH) {
          unsigned short h, l;
          split1(v, h, l);
          outH[(size_t)row * ldo + col] = h;
          outL[(size_t)row * ldo + col] = l;
        }
      }
    }
  }
}

__global__ __launch_bounds__(256) void mgemm_kernel(
    const unsigned short* Ah, const unsigned short* Al, int lda,
    const unsigned short* Gh, const unsigned short* Gl,
    const unsigned short* Bh, const unsigned short* Bl, int ldb,
    const float* bias, float* outF, unsigned short* outH, unsigned short* outL,
    int ldo, int colbase, int dup, int kchunks, int xchunks) {
  __shared__ unsigned short tiles[4][4096];
  mfma_gemm_dev<false>(tiles[0], tiles[1], tiles[2], tiles[3], Ah, Al, lda,
                       Gh, Gl, Bh, Bl, ldb, bias, outF, outH, outL, ldo,
                       colbase, dup, kchunks, xchunks, blockIdx.x * 64,
                       threadIdx.x);
}

// both layer-1 updates in one launch; A = f32 x (inline split)
__global__ __launch_bounds__(256) void update2m_kernel(
    const float* __restrict__ x,
    const unsigned short* auh, const unsigned short* aul,
    const unsigned short* adh, const unsigned short* adl,
    const unsigned short* U1uh, const unsigned short* U1ul,
    const unsigned short* U1dh, const unsigned short* U1dl,
    unsigned short* outH, unsigned short* outL) {
  __shared__ unsigned short tiles[4][4096];
  if (blockIdx.x < TB)
    mfma_gemm_dev<true>(tiles[0], tiles[1], tiles[2], tiles[3],
                        (const unsigned short*)x, nullptr, 128, auh, aul,
                        U1uh, U1ul, 192, nullptr, nullptr, outH, outL, 128,
                        0, 0, 3, 2, blockIdx.x * 64, threadIdx.x);
  else
    mfma_gemm_dev<true>(tiles[0], tiles[1], tiles[2], tiles[3],
                        (const unsigned short*)x, nullptr, 128, adh, adl,
                        U1dh, U1dl, 192, nullptr, nullptr, outH, outL, 128,
                        64, 0, 3, 2, (blockIdx.x - TB) * 64, threadIdx.x);
}

// ---------------------------------------------------------------------------
// prep: XCD-partitioned count (blocks [0,PB*8)) || weight conversion (32 blks)
// ---------------------------------------------------------------------------
__global__ __launch_bounds__(256) void prep_kernel(
    const int* __restrict__ src, const int* __restrict__ dst,
    int* __restrict__ rp_dst, int* __restrict__ rp_src,
    const float* __restrict__ U_u1, const float* __restrict__ U_d1,
    const float* __restrict__ W_u1, const float* __restrict__ W_d1,
    const float* __restrict__ W_u2, const float* __restrict__ U_u2,
    unsigned short* __restrict__ wbuf) {
  int bi = blockIdx.x;
  const int t = threadIdx.x;
  if (bi < PB * 8) {
    const int r = bi & 7;
    const int e = (bi >> 3) * 256 + t;
    if (e < NE) {
      const int s = src[e], d = dst[e];
      const unsigned lo = (unsigned)r * 6250u;
      if ((unsigned)(d - lo) < 6250u) atomicAdd(&rp_dst[d], 1);
      if ((unsigned)(s - lo) < 6250u) atomicAdd(&rp_src[s], 1);
    }
    return;
  }
  bi -= PB * 8;
  // weights: 8 matrices x 4 blocks each; convert + transpose (+presums)
  const int widx = bi >> 2;
  const int quad = bi & 3;
  const int Ks[8] = {192, 192, 128, 128, 128, 192, 64, 128};
  const int offs[8] = {WOFF_U1U, WOFF_U1D, WOFF_W1U, WOFF_W1D,
                       WOFF_W2U, WOFF_U2U, WOFF_WSUM, WOFF_USUM};
  const float* srcs[6] = {U_u1, U_d1, W_u1, W_d1, W_u2, U_u2};
  const int K = Ks[widx];
  const int off = offs[widx];
  const int qsz = K << 4;  // (K*64)/4
  const int beg = quad * qsz;
  for (int e = beg + t; e < beg + qsz; e += 256) {
    const int cc = e / K;
    const int kk = e - cc * K;
    float v;
    if (widx < 6) v = srcs[widx][kk * 64 + cc];
    else if (widx == 6) v = W_u2[kk * 64 + cc] + W_u2[(kk + 64) * 64 + cc];
    else v = (kk < 64) ? (U_u2[kk * 64 + cc] + U_u2[(kk + 64) * 64 + cc])
                       : U_u2[(kk + 64) * 64 + cc];
    unsigned short h, l;
    split1(v, h, l);
    wbuf[off + cc * K + kk] = h;
    wbuf[off + (K << 6) + cc * K + kk] = l;
  }
}

// ---------------------------------------------------------------------------
// CSR scan (2 blocks)
// ---------------------------------------------------------------------------
#define CHUNK 49
__global__ __launch_bounds__(1024) void scan_kernel(
    int* __restrict__ a0, int* __restrict__ a1) {
  int* a = (blockIdx.x == 0) ? a0 : a1;
  __shared__ int part[1024];
  const int t = threadIdx.x;
  const int beg = t * CHUNK;
  const int end = min(beg + CHUNK, NN);
  int s = 0;
  for (int i = beg; i < end; ++i) s += a[i];
  part[t] = s;
  __syncthreads();
  for (int off = 1; off < 1024; off <<= 1) {
    int add = (t >= off) ? part[t - off] : 0;
    __syncthreads();
    part[t] += add;
    __syncthreads();
  }
  int run = (t == 0) ? 0 : part[t - 1];
  for (int i = beg; i < end; ++i) {
    const int c = a[i];
    a[i] = run;
    run += c;
  }
}

// ---------------------------------------------------------------------------
// fused1: XCD-partitioned place (blocks [0,PB*8)) || trans_u1 || trans_d1
// transforms read f32 x with inline split
// ---------------------------------------------------------------------------
__global__ __launch_bounds__(256) void fused1_kernel(
    const int* __restrict__ src, const int* __restrict__ dst,
    int* __restrict__ rp_dst, int* __restrict__ rp_src,
    int* __restrict__ col_dst, int* __restrict__ col_src,
    const float* __restrict__ x,
    const unsigned short* W1uh, const unsigned short* W1ul,
    const unsigned short* W1dh, const unsigned short* W1dl,
    const float* __restrict__ b_u1, const float* __restrict__ b_d1,
    float* __restrict__ Yu, float* __restrict__ Yd) {
  __shared__ unsigned short tiles[4][4096];
  int bi = blockIdx.x;
  if (bi < PB * 8) {
    const int r = bi & 7;
    const int e = (bi >> 3) * 256 + threadIdx.x;
    if (e < NE) {
      const int s = src[e], d = dst[e];
      const unsigned lo = (unsigned)r * 6250u;
      if ((unsigned)(d - lo) < 6250u) col_dst[atomicAdd(&rp_dst[d], 1)] = s;
      if ((unsigned)(s - lo) < 6250u) col_src[atomicAdd(&rp_src[s], 1)] = d;
    }
    return;
  }
  bi -= PB * 8;
  if (bi < TB)
    mfma_gemm_dev<true>(tiles[0], tiles[1], tiles[2], tiles[3],
                        (const unsigned short*)x, nullptr, 128, nullptr,
                        nullptr, W1uh, W1ul, 128, b_u1, Yu, nullptr, nullptr,
                        64, 0, 0, 2, 2, bi * 64, threadIdx.x);
  else
    mfma_gemm_dev<true>(tiles[0], tiles[1], tiles[2], tiles[3],
                        (const unsigned short*)x, nullptr, 128, nullptr,
                        nullptr, W1dh, W1dl, 128, b_d1, Yd, nullptr, nullptr,
                        64, 0, 0, 2, 2, (bi - TB) * 64, threadIdx.x);
}

// ---------------------------------------------------------------------------
// pull-gather mean, 4x unrolled; writes f32 (AGGf) or bf16 hi/lo (aggh/aggl)
// ---------------------------------------------------------------------------
__device__ __forceinline__ void gather_dev(
    const float* __restrict__ Y, const int* __restrict__ rowptr,
    const int* __restrict__ col, float* __restrict__ AGGf,
    unsigned short* __restrict__ aggh, unsigned short* __restrict__ aggl,
    int node, int lane) {
  const int eg = lane >> 4;
  const int cq = (lane & 15) << 2;
  const int start = (node == 0) ? 0 : rowptr[node - 1];
  const int end = rowptr[node];
  float4 acc = make_float4(0.f, 0.f, 0.f, 0.f);
  int e = start + eg;
  for (; e + 12 < end; e += 16) {
    const int j0 = col[e];
    const int j1 = col[e + 4];
    const int j2 = col[e + 8];
    const int j3 = col[e + 12];
    const float4 y0 = *(const float4*)(Y + j0 * 64 + cq);
    const float4 y1 = *(const float4*)(Y + j1 * 64 + cq);
    const float4 y2 = *(const float4*)(Y + j2 * 64 + cq);
    const float4 y3 = *(const float4*)(Y + j3 * 64 + cq);
    acc.x += y0.x + y1.x + y2.x + y3.x;
    acc.y += y0.y + y1.y + y2.y + y3.y;
    acc.z += y0.z + y1.z + y2.z + y3.z;
    acc.w += y0.w + y1.w + y2.w + y3.w;
  }
  for (; e < end; e += 4) {
    const float4 y = *(const float4*)(Y + col[e] * 64 + cq);
    acc.x += y.x; acc.y += y.y; acc.z += y.z; acc.w += y.w;
  }
  acc.x += __shfl_xor(acc.x, 16);
  acc.y += __shfl_xor(acc.y, 16);
  acc.z += __shfl_xor(acc.z, 16);
  acc.w += __shfl_xor(acc.w, 16);
  acc.x += __shfl_xor(acc.x, 32);
  acc.y += __shfl_xor(acc.y, 32);
  acc.z += __shfl_xor(acc.z, 32);
  acc.w += __shfl_xor(acc.w, 32);
  if (eg == 0) {
    const float inv = 1.f / (float)max(end - start, 1);
    float4 o;
    o.x = acc.x * inv; o.y = acc.y * inv;
    o.z = acc.z * inv; o.w = acc.w * inv;
    if (AGGf) {
      *(float4*)(AGGf + node * 64 + cq) = o;
    } else {
      ushort4 h, l;
      split4(o, h, l);
      *(ushort4*)(aggh + node * 64 + cq) = h;
      *(ushort4*)(aggl + node * 64 + cq) = l;
    }
  }
}

__global__ __launch_bounds__(256) void gather_kernel(
    const float* __restrict__ Y, const int* __restrict__ rowptr,
    const int* __restrict__ col, float* __restrict__ AGGf,
    unsigned short* __restrict__ aggh, unsigned short* __restrict__ aggl) {
  gather_dev(Y, rowptr, col, AGGf, aggh, aggl,
             blockIdx.x * 4 + (threadIdx.x >> 6), threadIdx.x & 63);
}

__global__ __launch_bounds__(256) void gather2_kernel(
    const float* __restrict__ Yu, const int* __restrict__ rp_dst,
    const int* __restrict__ col_dst, unsigned short* auh, unsigned short* aul,
    const float* __restrict__ Yd, const int* __restrict__ rp_src,
    const int* __restrict__ col_src, unsigned short* adh, unsigned short* adl) {
  const int lane = threadIdx.x & 63;
  const int w = threadIdx.x >> 6;
  if (blockIdx.x < GB)
    gather_dev(Yu, rp_dst, col_dst, nullptr, auh, aul, blockIdx.x * 4 + w, lane);
  else
    gather_dev(Yd, rp_src, col_src, nullptr, adh, adl,
               (blockIdx.x - GB) * 4 + w, lane);
}

// ===========================================================================
// Fallback path (vector-f32 GEMM) for small workspaces
// ===========================================================================
__device__ __forceinline__ void gemm64_dev(
    float (*Xt)[68], float* Ws, const float* __restrict__ X, int ldx,
    const float* __restrict__ AGG, const float* __restrict__ W,
    const float* __restrict__ b, float* __restrict__ out, int ldo,
    int colbase, int dup, int kchunks, int xchunks, int row0, int tid) {
  const int tx = tid & 15, ty = tid >> 4;
  float acc[4][4] = {{0.f}};
  for (int c = 0; c < kchunks; ++c) {
    {
      const int rr = tid >> 2;
      const int cg = (tid & 3) << 4;
      const float* srcp;
      int ld, co;
      if (c < xchunks) { srcp = X; ld = ldx; co = c * 64; }
      else             { srcp = AGG; ld = 64; co = 0; }
      int row = row0 + rr;
      if (row > NN - 1) row = NN - 1;
      const float* g = srcp + row * ld + co + cg;
      const float4 v0 = *(const float4*)(g + 0);
      const float4 v1 = *(const float4*)(g + 4);
      const float4 v2 = *(const float4*)(g + 8);
      const float4 v3 = *(const float4*)(g + 12);
      Xt[cg + 0][rr] = v0.x;  Xt[cg + 1][rr] = v0.y;
      Xt[cg + 2][rr] = v0.z;  Xt[cg + 3][rr] = v0.w;
      Xt[cg + 4][rr] = v1.x;  Xt[cg + 5][rr] = v1.y;
      Xt[cg + 6][rr] = v1.z;  Xt[cg + 7][rr] = v1.w;
      Xt[cg + 8][rr] = v2.x;  Xt[cg + 9][rr] = v2.y;
      Xt[cg + 10][rr] = v2.z; Xt[cg + 11][rr] = v2.w;
      Xt[cg + 12][rr] = v3.x; Xt[cg + 13][rr] = v3.y;
      Xt[cg + 14][rr] = v3.z; Xt[cg + 15][rr] = v3.w;
      const float4* wg = (const float4*)(W + c * 64 * 64);
      float4* wl = (float4*)Ws;
      wl[tid] = wg[tid];
      wl[tid + 256] = wg[tid + 256];
      wl[tid + 512] = wg[tid + 512];
      wl[tid + 768] = wg[tid + 768];
    }
    __syncthreads();
#pragma unroll 8
    for (int kk = 0; kk < 64; ++kk) {
      const float4 a = *(const float4*)&Xt[kk][tx << 2];
      const float4 w = *(const float4*)&Ws[kk * 64 + (ty << 2)];
      acc[0][0] += a.x * w.x; acc[0][1] += a.x * w.y;
      acc[0][2] += a.x * w.z; acc[0][3] += a.x * w.w;
      acc[1][0] += a.y * w.x; acc[1][1] += a.y * w.y;
      acc[1][2] += a.y * w.z; acc[1][3] += a.y * w.w;
      acc[2][0] += a.z * w.x; acc[2][1] += a.z * w.y;
      acc[2][2] += a.z * w.z; acc[2][3] += a.z * w.w;
      acc[3][0] += a.w * w.x; acc[3][1] += a.w * w.y;
      acc[3][2] += a.w * w.z; acc[3][3] += a.w * w.w;
    }
    __syncthreads();
  }
  float4 bv = make_float4(0.f, 0.f, 0.f, 0.f);
  if (b) bv = *(const float4*)(b + (ty << 2));
#pragma unroll
  for (int i = 0; i < 4; ++i) {
    const int row = row0 + (tx << 2) + i;
    if (row < NN) {
      float4 o;
      o.x = fmaxf(acc[i][0] + bv.x, 0.f);
      o.y = fmaxf(acc[i][1] + bv.y, 0.f);
      o.z = fmaxf(acc[i][2] + bv.z, 0.f);
      o.w = fmaxf(acc[i][3] + bv.w, 0.f);
      *(float4*)(out + row * ldo + colbase + (ty << 2)) = o;
      if (dup) *(float4*)(out + row * ldo + 64 + (ty << 2)) = o;
    }
  }
}

__global__ __launch_bounds__(256) void gemm_kernel(
    const float* __restrict__ X, int ldx, const float* __restrict__ AGG,
    const float* __restrict__ W, const float* __restrict__ b,
    float* __restrict__ out, int ldo, int colbase, int dup,
    int kchunks, int xchunks) {
  __shared__ __align__(16) float Xt[64][68];
  __shared__ __align__(16) float Ws[4096];
  gemm64_dev(Xt, Ws, X, ldx, AGG, W, b, out, ldo, colbase, dup, kchunks,
             xchunks, blockIdx.x * 64, threadIdx.x);
}

__global__ __launch_bounds__(256) void fused0_kernel(
    const int* __restrict__ src, const int* __restrict__ dst,
    int* __restrict__ rp_dst, int* __restrict__ rp_src,
    const float* __restrict__ x,
    const float* __restrict__ W_u1, const float* __restrict__ b_u1,
    float* __restrict__ Y_u,
    const float* __restrict__ W_d1, const float* __restrict__ b_d1,
    float* __restrict__ Y_d) {
  __shared__ __align__(16) float Xt[64][68];
  __shared__ __align__(16) float Ws[4096];
  int bi = blockIdx.x;
  if (bi < PB) {
    const int e = bi * 256 + threadIdx.x;
    if (e < NE) {
      atomicAdd(&rp_dst[dst[e]], 1);
      atomicAdd(&rp_src[src[e]], 1);
    }
    return;
  }
  bi -= PB;
  if (bi < TB)
    gemm64_dev(Xt, Ws, x, 128, nullptr, W_u1, b_u1, Y_u, 64, 0, 0, 2, 2,
               bi * 64, threadIdx.x);
  else
    gemm64_dev(Xt, Ws, x, 128, nullptr, W_d1, b_d1, Y_d, 64, 0, 0, 2, 2,
               (bi - TB) * 64, threadIdx.x);
}

__global__ __launch_bounds__(256) void place_part_kernel(
    const int* __restrict__ src, const int* __restrict__ dst,
    int* __restrict__ rp_dst, int* __restrict__ rp_src,
    int* __restrict__ col_dst, int* __restrict__ col_src) {
  const int r = blockIdx.x & 7;
  const int e = (blockIdx.x >> 3) * 256 + threadIdx.x;
  if (e >= NE) return;
  const int s = src[e], d = dst[e];
  const unsigned lo = (unsigned)r * 6250u;
  if ((unsigned)(d - lo) < 6250u) col_dst[atomicAdd(&rp_dst[d], 1)] = s;
  if ((unsigned)(s - lo) < 6250u) col_src[atomicAdd(&rp_src[s], 1)] = d;
}

// ===========================================================================
extern "C" void kernel_launch(void* const* d_in, const int* in_sizes, int n_in,
                              void* d_out, int out_size, void* d_ws, size_t ws_size,
                              hipStream_t stream) {
  const float* x    = (const float*)d_in[0];
  const int*   ei   = (const int*)d_in[1];
  const float* W_u1 = (const float*)d_in[2];
  const float* b_u1 = (const float*)d_in[3];
  const float* U_u1 = (const float*)d_in[4];
  const float* W_d1 = (const float*)d_in[5];
  const float* b_d1 = (const float*)d_in[6];
  const float* U_d1 = (const float*)d_in[7];
  const float* W_u2 = (const float*)d_in[8];
  const float* b_u2 = (const float*)d_in[9];
  const float* U_u2 = (const float*)d_in[10];
  const int* src = ei;
  const int* dst = ei + NE;
  float* out = (float*)d_out;

  char* wsb = (char*)d_ws;
  int* rp_dst  = (int*)wsb;  wsb += NN * sizeof(int);
  int* rp_src  = (int*)wsb;  wsb += NN * sizeof(int);
  int* col_dst = (int*)wsb;  wsb += NE * sizeof(int);
  int* col_src = (int*)wsb;  wsb += NE * sizeof(int);

  const size_t needM = (size_t)(2 * NN + 2 * NE) * 4 +
                       (size_t)WBUF_USHORTS * 2 +
                       (size_t)NN * 64 * 4 * 2 +    // Yu, Yd
                       (size_t)NN * 64 * 2 * 4 +    // 4 agg bf16 planes
                       (size_t)NN * 64 * 2 * 2;     // O2h, O2l

  hipMemsetAsync(rp_dst, 0, 2 * NN * sizeof(int), stream);

  if (ws_size >= needM) {
    unsigned short* wbuf = (unsigned short*)wsb; wsb += (size_t)WBUF_USHORTS * 2;
    float* Yu = (float*)wsb;                     wsb += (size_t)NN * 64 * 4;
    float* Yd = (float*)wsb;                     wsb += (size_t)NN * 64 * 4;
    unsigned short* agg_uh = (unsigned short*)wsb; wsb += (size_t)NN * 64 * 2;
    unsigned short* agg_ul = (unsigned short*)wsb; wsb += (size_t)NN * 64 * 2;
    unsigned short* agg_dh = (unsigned short*)wsb; wsb += (size_t)NN * 64 * 2;
    unsigned short* agg_dl = (unsigned short*)wsb; wsb += (size_t)NN * 64 * 2;
    unsigned short* O2h = (unsigned short*)wsb;    wsb += (size_t)NN * 64 * 2;
    unsigned short* O2l = (unsigned short*)wsb;

    // aliases (sequential lifetime reuse)
    unsigned short* outh = (unsigned short*)Yu;  // [N][128] bf16 hi
    unsigned short* outl = (unsigned short*)Yd;  // [N][128] bf16 lo
    float* Y2 = (float*)agg_uh;                  // [N][64] f32 (spans uh+ul)
    unsigned short* agg2h = agg_dh;
    unsigned short* agg2l = agg_dl;

    const unsigned short* U1uh = wbuf + WOFF_U1U;
    const unsigned short* U1ul = wbuf + WOFF_U1U + 64 * 192;
    const unsigned short* U1dh = wbuf + WOFF_U1D;
    const unsigned short* U1dl = wbuf + WOFF_U1D + 64 * 192;
    const unsigned short* W1uh = wbuf + WOFF_W1U;
    const unsigned short* W1ul = wbuf + WOFF_W1U + 64 * 128;
    const unsigned short* W1dh = wbuf + WOFF_W1D;
    const unsigned short* W1dl = wbuf + WOFF_W1D + 64 * 128;
    const unsigned short* W2uh = wbuf + WOFF_W2U;
    const unsigned short* W2ul = wbuf + WOFF_W2U + 64 * 128;
    const unsigned short* U2uh = wbuf + WOFF_U2U;
    const unsigned short* U2ul = wbuf + WOFF_U2U + 64 * 192;
    const unsigned short* Wsh  = wbuf + WOFF_WSUM;
    const unsigned short* Wsl  = wbuf + WOFF_WSUM + 64 * 64;
    const unsigned short* Ush  = wbuf + WOFF_USUM;
    const unsigned short* Usl  = wbuf + WOFF_USUM + 64 * 128;

    prep_kernel<<<PB * 8 + 32, 256, 0, stream>>>(
        src, dst, rp_dst, rp_src, U_u1, U_d1, W_u1, W_d1, W_u2, U_u2, wbuf);
    scan_kernel<<<2, 1024, 0, stream>>>(rp_dst, rp_src);
    fused1_kernel<<<PB * 8 + 2 * TB, 256, 0, stream>>>(
        src, dst, rp_dst, rp_src, col_dst, col_src, x, W1uh, W1ul, W1dh,
        W1dl, b_u1, b_d1, Yu, Yd);
    // layer 1
    gather2_kernel<<<2 * GB, 256, 0, stream>>>(Yu, rp_dst, col_dst, agg_uh,
                                               agg_ul, Yd, rp_src, col_src,
                                               agg_dh, agg_dl);
    update2m_kernel<<<2 * TB, 256, 0, stream>>>(x, agg_uh, agg_ul, agg_dh,
                                                agg_dl, U1uh, U1ul, U1dh,
                                                U1dl, outh, outl);
    // round 2
    mgemm_kernel<<<TB, 256, 0, stream>>>(outh, outl, 128, nullptr, nullptr,
                                         W2uh, W2ul, 128, b_u2, Y2, nullptr,
                                         nullptr, 64, 0, 0, 2, 2);
    gather_kernel<<<GB, 256, 0, stream>>>(Y2, rp_dst, col_dst, nullptr,
                                          agg2h, agg2l);
    mgemm_kernel<<<TB, 256, 0, stream>>>(outh, outl, 128, agg2h, agg2l,
                                         U2uh, U2ul, 192, nullptr, nullptr,
                                         O2h, O2l, 64, 0, 0, 3, 2);
    // round 3 (h = [O2,O2] folded into presummed weights)
    mgemm_kernel<<<TB, 256, 0, stream>>>(O2h, O2l, 64, nullptr, nullptr,
                                         Wsh, Wsl, 64, b_u2, Y2, nullptr,
                                         nullptr, 64, 0, 0, 1, 1);
    gather_kernel<<<GB, 256, 0, stream>>>(Y2, rp_dst, col_dst, nullptr,
                                          agg2h, agg2l);
    mgemm_kernel<<<TB, 256, 0, stream>>>(O2h, O2l, 64, agg2h, agg2l,
                                         Ush, Usl, 128, nullptr, out,
                                         nullptr, nullptr, 128, 0, 1, 2, 1);
  } else {
    // fallback: vector-f32 path
    float* Y_u = (float*)wsb; wsb += (size_t)NN * 64 * sizeof(float);
    float* Y_d = (float*)wsb; wsb += (size_t)NN * 64 * sizeof(float);
    float* AGG = (float*)wsb;
    fused0_kernel<<<PB + 2 * TB, 256, 0, stream>>>(
        src, dst, rp_dst, rp_src, x, W_u1, b_u1, Y_u, W_d1, b_d1, Y_d);
    scan_kernel<<<2, 1024, 0, stream>>>(rp_dst, rp_src);
    place_part_kernel<<<PB * 8, 256, 0, stream>>>(src, dst, rp_dst, rp_src,
                                                  col_dst, col_src);
    gather_kernel<<<GB, 256, 0, stream>>>(Y_u, rp_dst, col_dst, AGG,
                                          nullptr, nullptr);
    gemm_kernel<<<TB, 256, 0, stream>>>(x, 128, AGG, U_u1, nullptr, out,
                                        128, 0, 0, 3, 2);
    gather_kernel<<<GB, 256, 0, stream>>>(Y_d, rp_src, col_src, AGG,
                                          nullptr, nullptr);
    gemm_kernel<<<TB, 256, 0, stream>>>(x, 128, AGG, U_d1, nullptr, out,
                                        128, 64, 0, 3, 2);
    for (int r = 0; r < 2; ++r) {
      gemm_kernel<<<TB, 256, 0, stream>>>(out, 128, nullptr, W_u2, b_u2,
                                          Y_u, 64, 0, 0, 2, 2);
      gather_kernel<<<GB, 256, 0, stream>>>(Y_u, rp_dst, col_dst, AGG,
                                            nullptr, nullptr);
      gemm_kernel<<<TB, 256, 0, stream>>>(out, 128, AGG, U_u2, nullptr,
                                          out, 128, 0, 1, 3, 2);
    }
  }
}

// Round 7
// 402.743 us; speedup vs baseline: 7.2912x; 1.0092x over previous
//
#include <hip/hip_runtime.h>

#define NN 50000
#define NE 800000
#define NP 2048            // strided edge-work blocks (256 per XCD range)
#define TB 782             // ceil(NN/64) gemm row-tile blocks
#define GBS 12504          // 8 * 1563 swizzled gather blocks (4 nodes each)

typedef __attribute__((ext_vector_type(8))) short bhalf8;
typedef __attribute__((ext_vector_type(4))) float floatx4;

// weight buffer offsets (ushort units); l plane = h + 64*K
#define WOFF_U1U 0
#define WOFF_U1D 24576
#define WOFF_W1U 49152
#define WOFF_W1D 65536
#define WOFF_W2U 81920
#define WOFF_U2U 98304
#define WOFF_WSUM 122880
#define WOFF_USUM 131072
#define WBUF_USHORTS 147456

// ---------------------------------------------------------------------------
// bf16 split helpers (RNE)
// ---------------------------------------------------------------------------
__device__ __forceinline__ unsigned short bf16hi(float v) {
  union { float f; unsigned u; } c; c.f = v;
  return (unsigned short)((c.u + 0x7FFFu + ((c.u >> 16) & 1u)) >> 16);
}
__device__ __forceinline__ float bf16tof(unsigned short h) {
  union { unsigned u; float f; } c; c.u = ((unsigned)h) << 16;
  return c.f;
}
__device__ __forceinline__ void split1(float v, unsigned short& h,
                                       unsigned short& l) {
  h = bf16hi(v);
  l = bf16hi(v - bf16tof(h));
}
__device__ __forceinline__ void split4(const float4 v, ushort4& h, ushort4& l) {
  split1(v.x, h.x, l.x);
  split1(v.y, h.y, l.y);
  split1(v.z, h.z, l.z);
  split1(v.w, h.w, l.w);
}
__device__ __forceinline__ void split8(const float4 v0, const float4 v1,
                                       uint4& H, uint4& L) {
  unsigned short h0, l0, h1, l1;
  split1(v0.x, h0, l0); split1(v0.y, h1, l1);
  H.x = (unsigned)h0 | ((unsigned)h1 << 16);
  L.x = (unsigned)l0 | ((unsigned)l1 << 16);
  split1(v0.z, h0, l0); split1(v0.w, h1, l1);
  H.y = (unsigned)h0 | ((unsigned)h1 << 16);
  L.y = (unsigned)l0 | ((unsigned)l1 << 16);
  split1(v1.x, h0, l0); split1(v1.y, h1, l1);
  H.z = (unsigned)h0 | ((unsigned)h1 << 16);
  L.z = (unsigned)l0 | ((unsigned)l1 << 16);
  split1(v1.z, h0, l0); split1(v1.w, h1, l1);
  H.w = (unsigned)h0 | ((unsigned)h1 << 16);
  L.w = (unsigned)l0 | ((unsigned)l1 << 16);
}

// swizzled LDS byte address for bf16 tile [64 rows][64 k] (128B rows)
#define SWZ(row, inrow) (((row) << 7) + ((inrow) ^ (((row)&7) << 4)))

// ---------------------------------------------------------------------------
// MFMA split-bf16 GEMM (single B): out = relu([A|G] @ B^T (+bias))
// ---------------------------------------------------------------------------
template <bool AF32>
__device__ __forceinline__ void mfma_gemm_dev(
    unsigned short* tAh, unsigned short* tAl,
    unsigned short* tBh, unsigned short* tBl,
    const unsigned short* __restrict__ Ah, const unsigned short* __restrict__ Al,
    int lda,
    const unsigned short* __restrict__ Gh, const unsigned short* __restrict__ Gl,
    const unsigned short* __restrict__ Bh, const unsigned short* __restrict__ Bl,
    int ldb, const float* __restrict__ bias,
    float* __restrict__ outF, unsigned short* __restrict__ outH,
    unsigned short* __restrict__ outL,
    int ldo, int colbase, int dup, int kchunks, int xchunks,
    int row0, int tid) {
  const int lane = tid & 63;
  const int wm = tid >> 6;
  const int m = lane & 15;
  const int kg = lane >> 4;
  floatx4 acc[4];
#pragma unroll
  for (int i = 0; i < 4; ++i) acc[i] = (floatx4){0.f, 0.f, 0.f, 0.f};

  for (int c = 0; c < kchunks; ++c) {
#pragma unroll
    for (int q = tid; q < 512; q += 256) {
      const int row = q >> 3, slot = q & 7;
      int gr = row0 + row;
      gr = (gr > NN - 1) ? NN - 1 : gr;
      const int ad = SWZ(row, slot << 4);
      if (AF32 && c < xchunks) {
        const float* f = (const float*)Ah;
        const size_t go = (size_t)gr * lda + (c << 6) + slot * 8;
        const float4 v0 = *(const float4*)(f + go);
        const float4 v1 = *(const float4*)(f + go + 4);
        uint4 H, L;
        split8(v0, v1, H, L);
        *(uint4*)((char*)tAh + ad) = H;
        *(uint4*)((char*)tAl + ad) = L;
      } else {
        const unsigned short* sh;
        const unsigned short* sl;
        int ld, kc;
        if (c < xchunks) { sh = Ah; sl = Al; ld = lda; kc = c << 6; }
        else             { sh = Gh; sl = Gl; ld = 64;  kc = 0; }
        const size_t go = (size_t)gr * ld + kc + slot * 8;
        *(uint4*)((char*)tAh + ad) = *(const uint4*)(sh + go);
        *(uint4*)((char*)tAl + ad) = *(const uint4*)(sl + go);
      }
      const size_t gob = (size_t)row * ldb + (c << 6) + slot * 8;
      *(uint4*)((char*)tBh + ad) = *(const uint4*)(Bh + gob);
      *(uint4*)((char*)tBl + ad) = *(const uint4*)(Bl + gob);
    }
    __syncthreads();
#pragma unroll
    for (int ks = 0; ks < 2; ++ks) {
      const int inrow = (ks << 6) + (kg << 4);
      const int rA = (wm << 4) + m;
      const bhalf8 ah = *(const bhalf8*)((const char*)tAh + SWZ(rA, inrow));
      const bhalf8 al = *(const bhalf8*)((const char*)tAl + SWZ(rA, inrow));
#pragma unroll
      for (int nt = 0; nt < 4; ++nt) {
        const int rB = (nt << 4) + m;
        const bhalf8 bh = *(const bhalf8*)((const char*)tBh + SWZ(rB, inrow));
        const bhalf8 bl = *(const bhalf8*)((const char*)tBl + SWZ(rB, inrow));
        acc[nt] = __builtin_amdgcn_mfma_f32_16x16x32_bf16(ah, bh, acc[nt], 0, 0, 0);
        acc[nt] = __builtin_amdgcn_mfma_f32_16x16x32_bf16(ah, bl, acc[nt], 0, 0, 0);
        acc[nt] = __builtin_amdgcn_mfma_f32_16x16x32_bf16(al, bh, acc[nt], 0, 0, 0);
      }
    }
    __syncthreads();
  }
#pragma unroll
  for (int nt = 0; nt < 4; ++nt) {
    const int col = colbase + (nt << 4) + m;
    const float bv = bias ? bias[(nt << 4) + m] : 0.f;
#pragma unroll
    for (int r = 0; r < 4; ++r) {
      const int row = row0 + (wm << 4) + (kg << 2) + r;
      if (row < NN) {
        const float v = fmaxf(acc[nt][r] + bv, 0.f);
        if (outF) {
          outF[(size_t)row * ldo + col] = v;
          if (dup) outF[(size_t)row * ldo + col + 64] = v;
        }
        if (outH) {
          unsigned short h, l;
          split1(v, h, l);
          outH[(size_t)row * ldo + col] = h;
          outL[(size_t)row * ldo + col] = l;
        }
      }
    }
  }
}

// ---------------------------------------------------------------------------
// Dual-output transform: stage x tile once, apply W_u1 AND W_d1
// ---------------------------------------------------------------------------
__device__ __forceinline__ void trans2_dev(
    unsigned short* tAh, unsigned short* tAl,
    unsigned short* tBuh, unsigned short* tBul,
    unsigned short* tBdh, unsigned short* tBdl,
    const float* __restrict__ x,
    const unsigned short* __restrict__ Wuh, const unsigned short* __restrict__ Wul,
    const unsigned short* __restrict__ Wdh, const unsigned short* __restrict__ Wdl,
    const float* __restrict__ bu, const float* __restrict__ bd,
    float* __restrict__ Yu, float* __restrict__ Yd, int row0, int tid) {
  const int lane = tid & 63;
  const int wm = tid >> 6;
  const int m = lane & 15;
  const int kg = lane >> 4;
  floatx4 accU[4], accD[4];
#pragma unroll
  for (int i = 0; i < 4; ++i) {
    accU[i] = (floatx4){0.f, 0.f, 0.f, 0.f};
    accD[i] = (floatx4){0.f, 0.f, 0.f, 0.f};
  }
  for (int c = 0; c < 2; ++c) {
#pragma unroll
    for (int q = tid; q < 512; q += 256) {
      const int row = q >> 3, slot = q & 7;
      int gr = row0 + row;
      gr = (gr > NN - 1) ? NN - 1 : gr;
      const int ad = SWZ(row, slot << 4);
      const size_t go = (size_t)gr * 128 + (c << 6) + slot * 8;
      const float4 v0 = *(const float4*)(x + go);
      const float4 v1 = *(const float4*)(x + go + 4);
      uint4 H, L;
      split8(v0, v1, H, L);
      *(uint4*)((char*)tAh + ad) = H;
      *(uint4*)((char*)tAl + ad) = L;
      const size_t gob = (size_t)row * 128 + (c << 6) + slot * 8;
      *(uint4*)((char*)tBuh + ad) = *(const uint4*)(Wuh + gob);
      *(uint4*)((char*)tBul + ad) = *(const uint4*)(Wul + gob);
      *(uint4*)((char*)tBdh + ad) = *(const uint4*)(Wdh + gob);
      *(uint4*)((char*)tBdl + ad) = *(const uint4*)(Wdl + gob);
    }
    __syncthreads();
#pragma unroll
    for (int ks = 0; ks < 2; ++ks) {
      const int inrow = (ks << 6) + (kg << 4);
      const int rA = (wm << 4) + m;
      const bhalf8 ah = *(const bhalf8*)((const char*)tAh + SWZ(rA, inrow));
      const bhalf8 al = *(const bhalf8*)((const char*)tAl + SWZ(rA, inrow));
#pragma unroll
      for (int nt = 0; nt < 4; ++nt) {
        const int rB = (nt << 4) + m;
        const int adB = SWZ(rB, inrow);
        const bhalf8 buh = *(const bhalf8*)((const char*)tBuh + adB);
        const bhalf8 bul = *(const bhalf8*)((const char*)tBul + adB);
        accU[nt] = __builtin_amdgcn_mfma_f32_16x16x32_bf16(ah, buh, accU[nt], 0, 0, 0);
        accU[nt] = __builtin_amdgcn_mfma_f32_16x16x32_bf16(ah, bul, accU[nt], 0, 0, 0);
        accU[nt] = __builtin_amdgcn_mfma_f32_16x16x32_bf16(al, buh, accU[nt], 0, 0, 0);
        const bhalf8 bdh = *(const bhalf8*)((const char*)tBdh + adB);
        const bhalf8 bdl = *(const bhalf8*)((const char*)tBdl + adB);
        accD[nt] = __builtin_amdgcn_mfma_f32_16x16x32_bf16(ah, bdh, accD[nt], 0, 0, 0);
        accD[nt] = __builtin_amdgcn_mfma_f32_16x16x32_bf16(ah, bdl, accD[nt], 0, 0, 0);
        accD[nt] = __builtin_amdgcn_mfma_f32_16x16x32_bf16(al, bdh, accD[nt], 0, 0, 0);
      }
    }
    __syncthreads();
  }
#pragma unroll
  for (int nt = 0; nt < 4; ++nt) {
    const int col = (nt << 4) + m;
    const float bvu = bu[col];
    const float bvd = bd[col];
#pragma unroll
    for (int r = 0; r < 4; ++r) {
      const int row = row0 + (wm << 4) + (kg << 2) + r;
      if (row < NN) {
        Yu[(size_t)row * 64 + col] = fmaxf(accU[nt][r] + bvu, 0.f);
        Yd[(size_t)row * 64 + col] = fmaxf(accD[nt][r] + bvd, 0.f);
      }
    }
  }
}

__global__ __launch_bounds__(256) void mgemm_kernel(
    const unsigned short* Ah, const unsigned short* Al, int lda,
    const unsigned short* Gh, const unsigned short* Gl,
    const unsigned short* Bh, const unsigned short* Bl, int ldb,
    const float* bias, float* outF, unsigned short* outH, unsigned short* outL,
    int ldo, int colbase, int dup, int kchunks, int xchunks) {
  __shared__ unsigned short tiles[4][4096];
  mfma_gemm_dev<false>(tiles[0], tiles[1], tiles[2], tiles[3], Ah, Al, lda,
                       Gh, Gl, Bh, Bl, ldb, bias, outF, outH, outL, ldo,
                       colbase, dup, kchunks, xchunks, blockIdx.x * 64,
                       threadIdx.x);
}

// both layer-1 updates in one launch; A = f32 x (inline split)
__global__ __launch_bounds__(256) void update2m_kernel(
    const float* __restrict__ x,
    const unsigned short* auh, const unsigned short* aul,
    const unsigned short* adh, const unsigned short* adl,
    const unsigned short* U1uh, const unsigned short* U1ul,
    const unsigned short* U1dh, const unsigned short* U1dl,
    unsigned short* outH, unsigned short* outL) {
  __shared__ unsigned short tiles[4][4096];
  if (blockIdx.x < TB)
    mfma_gemm_dev<true>(tiles[0], tiles[1], tiles[2], tiles[3],
                        (const unsigned short*)x, nullptr, 128, auh, aul,
                        U1uh, U1ul, 192, nullptr, nullptr, outH, outL, 128,
                        0, 0, 3, 2, blockIdx.x * 64, threadIdx.x);
  else
    mfma_gemm_dev<true>(tiles[0], tiles[1], tiles[2], tiles[3],
                        (const unsigned short*)x, nullptr, 128, adh, adl,
                        U1dh, U1dl, 192, nullptr, nullptr, outH, outL, 128,
                        64, 0, 3, 2, (blockIdx.x - TB) * 64, threadIdx.x);
}

// ---------------------------------------------------------------------------
// pack: (src,dst) int32 pairs -> u32 (s | d<<16)  [node ids < 65536]
// ---------------------------------------------------------------------------
__global__ __launch_bounds__(256) void pack_kernel(
    const int* __restrict__ src, const int* __restrict__ dst,
    unsigned* __restrict__ epack) {
  for (int e = blockIdx.x * 256 + threadIdx.x; e < NE; e += 1024 * 256)
    epack[e] = (unsigned)src[e] | ((unsigned)dst[e] << 16);
}

// ---------------------------------------------------------------------------
// prep: XCD-partitioned strided count (blocks [0,NP)) || weights (32 blocks)
// ---------------------------------------------------------------------------
__global__ __launch_bounds__(256) void prep_kernel(
    const unsigned* __restrict__ epack,
    int* __restrict__ rp_dst, int* __restrict__ rp_src,
    const float* __restrict__ U_u1, const float* __restrict__ U_d1,
    const float* __restrict__ W_u1, const float* __restrict__ W_d1,
    const float* __restrict__ W_u2, const float* __restrict__ U_u2,
    unsigned short* __restrict__ wbuf) {
  int bi = blockIdx.x;
  const int t = threadIdx.x;
  if (bi < NP) {
    const unsigned lo = (unsigned)(bi & 7) * 6250u;
    for (int e = (bi >> 3) * 256 + t; e < NE; e += 65536) {
      const unsigned v = epack[e];
      const unsigned s = v & 0xFFFFu, d = v >> 16;
      if (d - lo < 6250u) atomicAdd(&rp_dst[d], 1);
      if (s - lo < 6250u) atomicAdd(&rp_src[s], 1);
    }
    return;
  }
  bi -= NP;
  const int widx = bi >> 2;
  const int quad = bi & 3;
  const int Ks[8] = {192, 192, 128, 128, 128, 192, 64, 128};
  const int offs[8] = {WOFF_U1U, WOFF_U1D, WOFF_W1U, WOFF_W1D,
                       WOFF_W2U, WOFF_U2U, WOFF_WSUM, WOFF_USUM};
  const float* srcs[6] = {U_u1, U_d1, W_u1, W_d1, W_u2, U_u2};
  const int K = Ks[widx];
  const int off = offs[widx];
  const int qsz = K << 4;
  const int beg = quad * qsz;
  for (int e = beg + t; e < beg + qsz; e += 256) {
    const int cc = e / K;
    const int kk = e - cc * K;
    float v;
    if (widx < 6) v = srcs[widx][kk * 64 + cc];
    else if (widx == 6) v = W_u2[kk * 64 + cc] + W_u2[(kk + 64) * 64 + cc];
    else v = (kk < 64) ? (U_u2[kk * 64 + cc] + U_u2[(kk + 64) * 64 + cc])
                       : U_u2[(kk + 64) * 64 + cc];
    unsigned short h, l;
    split1(v, h, l);
    wbuf[off + cc * K + kk] = h;
    wbuf[off + (K << 6) + cc * K + kk] = l;
  }
}

// ---------------------------------------------------------------------------
// CSR scan (2 blocks)
// ---------------------------------------------------------------------------
#define CHUNK 49
__global__ __launch_bounds__(1024) void scan_kernel(
    int* __restrict__ a0, int* __restrict__ a1) {
  int* a = (blockIdx.x == 0) ? a0 : a1;
  __shared__ int part[1024];
  const int t = threadIdx.x;
  const int beg = t * CHUNK;
  const int end = min(beg + CHUNK, NN);
  int s = 0;
  for (int i = beg; i < end; ++i) s += a[i];
  part[t] = s;
  __syncthreads();
  for (int off = 1; off < 1024; off <<= 1) {
    int add = (t >= off) ? part[t - off] : 0;
    __syncthreads();
    part[t] += add;
    __syncthreads();
  }
  int run = (t == 0) ? 0 : part[t - 1];
  for (int i = beg; i < end; ++i) {
    const int c = a[i];
    a[i] = run;
    run += c;
  }
}

// ---------------------------------------------------------------------------
// strided XCD-partitioned place (device helper shared by fused kernels)
// ---------------------------------------------------------------------------
__device__ __forceinline__ void place_dev(
    const unsigned* __restrict__ epack,
    int* __restrict__ rp_dst, int* __restrict__ rp_src,
    unsigned short* __restrict__ col_dst, unsigned short* __restrict__ col_src,
    int bi, int tid) {
  const unsigned lo = (unsigned)(bi & 7) * 6250u;
  for (int e = (bi >> 3) * 256 + tid; e < NE; e += 65536) {
    const unsigned v = epack[e];
    const unsigned s = v & 0xFFFFu, d = v >> 16;
    if (d - lo < 6250u) col_dst[atomicAdd(&rp_dst[d], 1)] = (unsigned short)s;
    if (s - lo < 6250u) col_src[atomicAdd(&rp_src[s], 1)] = (unsigned short)d;
  }
}

// ---------------------------------------------------------------------------
// fused1: strided place (blocks [0,NP)) || dual-output transform (TB blocks)
// ---------------------------------------------------------------------------
__global__ __launch_bounds__(256) void fused1_kernel(
    const unsigned* __restrict__ epack,
    int* __restrict__ rp_dst, int* __restrict__ rp_src,
    unsigned short* __restrict__ col_dst, unsigned short* __restrict__ col_src,
    const float* __restrict__ x,
    const unsigned short* W1uh, const unsigned short* W1ul,
    const unsigned short* W1dh, const unsigned short* W1dl,
    const float* __restrict__ b_u1, const float* __restrict__ b_d1,
    float* __restrict__ Yu, float* __restrict__ Yd) {
  __shared__ unsigned short tiles[6][4096];
  int bi = blockIdx.x;
  if (bi < NP) {
    place_dev(epack, rp_dst, rp_src, col_dst, col_src, bi, threadIdx.x);
    return;
  }
  bi -= NP;
  trans2_dev(tiles[0], tiles[1], tiles[2], tiles[3], tiles[4], tiles[5],
             x, W1uh, W1ul, W1dh, W1dl, b_u1, b_d1, Yu, Yd,
             bi * 64, threadIdx.x);
}

// ---------------------------------------------------------------------------
// pull-gather mean (u16 col), XCD-aligned node swizzle
// seg%8 = XCD range r; node = r*6250 + (seg>>3)*4 + wave
// ---------------------------------------------------------------------------
__device__ __forceinline__ void gather_dev(
    const float* __restrict__ Y, const int* __restrict__ rowptr,
    const unsigned short* __restrict__ col, float* __restrict__ AGGf,
    unsigned short* __restrict__ aggh, unsigned short* __restrict__ aggl,
    int seg, int tid) {
  const int w = tid >> 6;
  const int lane = tid & 63;
  const int off = (seg >> 3) * 4 + w;
  if (off >= 6250) return;
  const int node = (seg & 7) * 6250 + off;
  const int eg = lane >> 4;
  const int cq = (lane & 15) << 2;
  const int start = (node == 0) ? 0 : rowptr[node - 1];
  const int end = rowptr[node];
  float4 acc = make_float4(0.f, 0.f, 0.f, 0.f);
  int e = start + eg;
  for (; e + 12 < end; e += 16) {
    const int j0 = col[e];
    const int j1 = col[e + 4];
    const int j2 = col[e + 8];
    const int j3 = col[e + 12];
    const float4 y0 = *(const float4*)(Y + j0 * 64 + cq);
    const float4 y1 = *(const float4*)(Y + j1 * 64 + cq);
    const float4 y2 = *(const float4*)(Y + j2 * 64 + cq);
    const float4 y3 = *(const float4*)(Y + j3 * 64 + cq);
    acc.x += y0.x + y1.x + y2.x + y3.x;
    acc.y += y0.y + y1.y + y2.y + y3.y;
    acc.z += y0.z + y1.z + y2.z + y3.z;
    acc.w += y0.w + y1.w + y2.w + y3.w;
  }
  for (; e < end; e += 4) {
    const float4 y = *(const float4*)(Y + col[e] * 64 + cq);
    acc.x += y.x; acc.y += y.y; acc.z += y.z; acc.w += y.w;
  }
  acc.x += __shfl_xor(acc.x, 16);
  acc.y += __shfl_xor(acc.y, 16);
  acc.z += __shfl_xor(acc.z, 16);
  acc.w += __shfl_xor(acc.w, 16);
  acc.x += __shfl_xor(acc.x, 32);
  acc.y += __shfl_xor(acc.y, 32);
  acc.z += __shfl_xor(acc.z, 32);
  acc.w += __shfl_xor(acc.w, 32);
  if (eg == 0) {
    const float inv = 1.f / (float)max(end - start, 1);
    float4 o;
    o.x = acc.x * inv; o.y = acc.y * inv;
    o.z = acc.z * inv; o.w = acc.w * inv;
    if (AGGf) {
      *(float4*)(AGGf + node * 64 + cq) = o;
    } else {
      ushort4 h, l;
      split4(o, h, l);
      *(ushort4*)(aggh + node * 64 + cq) = h;
      *(ushort4*)(aggl + node * 64 + cq) = l;
    }
  }
}

__global__ __launch_bounds__(256) void gather_kernel(
    const float* __restrict__ Y, const int* __restrict__ rowptr,
    const unsigned short* __restrict__ col, float* __restrict__ AGGf,
    unsigned short* __restrict__ aggh, unsigned short* __restrict__ aggl) {
  gather_dev(Y, rowptr, col, AGGf, aggh, aggl, blockIdx.x, threadIdx.x);
}

__global__ __launch_bounds__(256) void gather2_kernel(
    const float* __restrict__ Yu, const int* __restrict__ rp_dst,
    const unsigned short* __restrict__ col_dst,
    unsigned short* auh, unsigned short* aul,
    const float* __restrict__ Yd, const int* __restrict__ rp_src,
    const unsigned short* __restrict__ col_src,
    unsigned short* adh, unsigned short* adl) {
  if (blockIdx.x < GBS)
    gather_dev(Yu, rp_dst, col_dst, nullptr, auh, aul, blockIdx.x, threadIdx.x);
  else
    gather_dev(Yd, rp_src, col_src, nullptr, adh, adl, blockIdx.x - GBS,
               threadIdx.x);
}

// ===========================================================================
// Fallback path (vector-f32 GEMM) for small workspaces
// ===========================================================================
__device__ __forceinline__ void gemm64_dev(
    float (*Xt)[68], float* Ws, const float* __restrict__ X, int ldx,
    const float* __restrict__ AGG, const float* __restrict__ W,
    const float* __restrict__ b, float* __restrict__ out, int ldo,
    int colbase, int dup, int kchunks, int xchunks, int row0, int tid) {
  const int tx = tid & 15, ty = tid >> 4;
  float acc[4][4] = {{0.f}};
  for (int c = 0; c < kchunks; ++c) {
    {
      const int rr = tid >> 2;
      const int cg = (tid & 3) << 4;
      const float* srcp;
      int ld, co;
      if (c < xchunks) { srcp = X; ld = ldx; co = c * 64; }
      else             { srcp = AGG; ld = 64; co = 0; }
      int row = row0 + rr;
      if (row > NN - 1) row = NN - 1;
      const float* g = srcp + row * ld + co + cg;
      const float4 v0 = *(const float4*)(g + 0);
      const float4 v1 = *(const float4*)(g + 4);
      const float4 v2 = *(const float4*)(g + 8);
      const float4 v3 = *(const float4*)(g + 12);
      Xt[cg + 0][rr] = v0.x;  Xt[cg + 1][rr] = v0.y;
      Xt[cg + 2][rr] = v0.z;  Xt[cg + 3][rr] = v0.w;
      Xt[cg + 4][rr] = v1.x;  Xt[cg + 5][rr] = v1.y;
      Xt[cg + 6][rr] = v1.z;  Xt[cg + 7][rr] = v1.w;
      Xt[cg + 8][rr] = v2.x;  Xt[cg + 9][rr] = v2.y;
      Xt[cg + 10][rr] = v2.z; Xt[cg + 11][rr] = v2.w;
      Xt[cg + 12][rr] = v3.x; Xt[cg + 13][rr] = v3.y;
      Xt[cg + 14][rr] = v3.z; Xt[cg + 15][rr] = v3.w;
      const float4* wg = (const float4*)(W + c * 64 * 64);
      float4* wl = (float4*)Ws;
      wl[tid] = wg[tid];
      wl[tid + 256] = wg[tid + 256];
      wl[tid + 512] = wg[tid + 512];
      wl[tid + 768] = wg[tid + 768];
    }
    __syncthreads();
#pragma unroll 8
    for (int kk = 0; kk < 64; ++kk) {
      const float4 a = *(const float4*)&Xt[kk][tx << 2];
      const float4 w = *(const float4*)&Ws[kk * 64 + (ty << 2)];
      acc[0][0] += a.x * w.x; acc[0][1] += a.x * w.y;
      acc[0][2] += a.x * w.z; acc[0][3] += a.x * w.w;
      acc[1][0] += a.y * w.x; acc[1][1] += a.y * w.y;
      acc[1][2] += a.y * w.z; acc[1][3] += a.y * w.w;
      acc[2][0] += a.z * w.x; acc[2][1] += a.z * w.y;
      acc[2][2] += a.z * w.z; acc[2][3] += a.z * w.w;
      acc[3][0] += a.w * w.x; acc[3][1] += a.w * w.y;
      acc[3][2] += a.w * w.z; acc[3][3] += a.w * w.w;
    }
    __syncthreads();
  }
  float4 bv = make_float4(0.f, 0.f, 0.f, 0.f);
  if (b) bv = *(const float4*)(b + (ty << 2));
#pragma unroll
  for (int i = 0; i < 4; ++i) {
    const int row = row0 + (tx << 2) + i;
    if (row < NN) {
      float4 o;
      o.x = fmaxf(acc[i][0] + bv.x, 0.f);
      o.y = fmaxf(acc[i][1] + bv.y, 0.f);
      o.z = fmaxf(acc[i][2] + bv.z, 0.f);
      o.w = fmaxf(acc[i][3] + bv.w, 0.f);
      *(float4*)(out + row * ldo + colbase + (ty << 2)) = o;
      if (dup) *(float4*)(out + row * ldo + 64 + (ty << 2)) = o;
    }
  }
}

__global__ __launch_bounds__(256) void gemm_kernel(
    const float* __restrict__ X, int ldx, const float* __restrict__ AGG,
    const float* __restrict__ W, const float* __restrict__ b,
    float* __restrict__ out, int ldo, int colbase, int dup,
    int kchunks, int xchunks) {
  __shared__ __align__(16) float Xt[64][68];
  __shared__ __align__(16) float Ws[4096];
  gemm64_dev(Xt, Ws, X, ldx, AGG, W, b, out, ldo, colbase, dup, kchunks,
             xchunks, blockIdx.x * 64, threadIdx.x);
}

// fallback count (strided, partitioned)
__global__ __launch_bounds__(256) void count_kernel(
    const unsigned* __restrict__ epack,
    int* __restrict__ rp_dst, int* __restrict__ rp_src) {
  const int bi = blockIdx.x;
  const unsigned lo = (unsigned)(bi & 7) * 6250u;
  for (int e = (bi >> 3) * 256 + threadIdx.x; e < NE; e += 65536) {
    const unsigned v = epack[e];
    const unsigned s = v & 0xFFFFu, d = v >> 16;
    if (d - lo < 6250u) atomicAdd(&rp_dst[d], 1);
    if (s - lo < 6250u) atomicAdd(&rp_src[s], 1);
  }
}

// fallback fused0: place || vector transforms
__global__ __launch_bounds__(256) void fused0_kernel(
    const unsigned* __restrict__ epack,
    int* __restrict__ rp_dst, int* __restrict__ rp_src,
    unsigned short* __restrict__ col_dst, unsigned short* __restrict__ col_src,
    const float* __restrict__ x,
    const float* __restrict__ W_u1, const float* __restrict__ b_u1,
    float* __restrict__ Y_u,
    const float* __restrict__ W_d1, const float* __restrict__ b_d1,
    float* __restrict__ Y_d) {
  __shared__ __align__(16) float Xt[64][68];
  __shared__ __align__(16) float Ws[4096];
  int bi = blockIdx.x;
  if (bi < NP) {
    place_dev(epack, rp_dst, rp_src, col_dst, col_src, bi, threadIdx.x);
    return;
  }
  bi -= NP;
  if (bi < TB)
    gemm64_dev(Xt, Ws, x, 128, nullptr, W_u1, b_u1, Y_u, 64, 0, 0, 2, 2,
               bi * 64, threadIdx.x);
  else
    gemm64_dev(Xt, Ws, x, 128, nullptr, W_d1, b_d1, Y_d, 64, 0, 0, 2, 2,
               (bi - TB) * 64, threadIdx.x);
}

// ===========================================================================
extern "C" void kernel_launch(void* const* d_in, const int* in_sizes, int n_in,
                              void* d_out, int out_size, void* d_ws, size_t ws_size,
                              hipStream_t stream) {
  const float* x    = (const float*)d_in[0];
  const int*   ei   = (const int*)d_in[1];
  const float* W_u1 = (const float*)d_in[2];
  const float* b_u1 = (const float*)d_in[3];
  const float* U_u1 = (const float*)d_in[4];
  const float* W_d1 = (const float*)d_in[5];
  const float* b_d1 = (const float*)d_in[6];
  const float* U_d1 = (const float*)d_in[7];
  const float* W_u2 = (const float*)d_in[8];
  const float* b_u2 = (const float*)d_in[9];
  const float* U_u2 = (const float*)d_in[10];
  const int* src = ei;
  const int* dst = ei + NE;
  float* out = (float*)d_out;

  char* wsb = (char*)d_ws;
  int* rp_dst  = (int*)wsb;              wsb += NN * sizeof(int);
  int* rp_src  = (int*)wsb;              wsb += NN * sizeof(int);
  unsigned* epack = (unsigned*)wsb;      wsb += (size_t)NE * 4;
  unsigned short* col_dst = (unsigned short*)wsb; wsb += (size_t)NE * 2;
  unsigned short* col_src = (unsigned short*)wsb; wsb += (size_t)NE * 2;

  const size_t needM = (size_t)2 * NN * 4 + (size_t)NE * 8 +
                       (size_t)WBUF_USHORTS * 2 +
                       (size_t)NN * 64 * 4 * 2 +    // Yu, Yd
                       (size_t)NN * 64 * 2 * 4 +    // 4 agg bf16 planes
                       (size_t)NN * 64 * 2 * 2;     // O2h, O2l

  hipMemsetAsync(rp_dst, 0, 2 * NN * sizeof(int), stream);
  pack_kernel<<<1024, 256, 0, stream>>>(src, dst, epack);

  if (ws_size >= needM) {
    unsigned short* wbuf = (unsigned short*)wsb; wsb += (size_t)WBUF_USHORTS * 2;
    float* Yu = (float*)wsb;                     wsb += (size_t)NN * 64 * 4;
    float* Yd = (float*)wsb;                     wsb += (size_t)NN * 64 * 4;
    unsigned short* agg_uh = (unsigned short*)wsb; wsb += (size_t)NN * 64 * 2;
    unsigned short* agg_ul = (unsigned short*)wsb; wsb += (size_t)NN * 64 * 2;
    unsigned short* agg_dh = (unsigned short*)wsb; wsb += (size_t)NN * 64 * 2;
    unsigned short* agg_dl = (unsigned short*)wsb; wsb += (size_t)NN * 64 * 2;
    unsigned short* O2h = (unsigned short*)wsb;    wsb += (size_t)NN * 64 * 2;
    unsigned short* O2l = (unsigned short*)wsb;

    // aliases (sequential lifetime reuse)
    unsigned short* outh = (unsigned short*)Yu;  // [N][128] bf16 hi
    unsigned short* outl = (unsigned short*)Yd;  // [N][128] bf16 lo
    float* Y2 = (float*)agg_uh;                  // [N][64] f32 (spans uh+ul)
    unsigned short* agg2h = agg_dh;
    unsigned short* agg2l = agg_dl;

    const unsigned short* U1uh = wbuf + WOFF_U1U;
    const unsigned short* U1ul = wbuf + WOFF_U1U + 64 * 192;
    const unsigned short* U1dh = wbuf + WOFF_U1D;
    const unsigned short* U1dl = wbuf + WOFF_U1D + 64 * 192;
    const unsigned short* W1uh = wbuf + WOFF_W1U;
    const unsigned short* W1ul = wbuf + WOFF_W1U + 64 * 128;
    const unsigned short* W1dh = wbuf + WOFF_W1D;
    const unsigned short* W1dl = wbuf + WOFF_W1D + 64 * 128;
    const unsigned short* W2uh = wbuf + WOFF_W2U;
    const unsigned short* W2ul = wbuf + WOFF_W2U + 64 * 128;
    const unsigned short* U2uh = wbuf + WOFF_U2U;
    const unsigned short* U2ul = wbuf + WOFF_U2U + 64 * 192;
    const unsigned short* Wsh  = wbuf + WOFF_WSUM;
    const unsigned short* Wsl  = wbuf + WOFF_WSUM + 64 * 64;
    const unsigned short* Ush  = wbuf + WOFF_USUM;
    const unsigned short* Usl  = wbuf + WOFF_USUM + 64 * 128;

    prep_kernel<<<NP + 32, 256, 0, stream>>>(
        epack, rp_dst, rp_src, U_u1, U_d1, W_u1, W_d1, W_u2, U_u2, wbuf);
    scan_kernel<<<2, 1024, 0, stream>>>(rp_dst, rp_src);
    fused1_kernel<<<NP + TB, 256, 0, stream>>>(
        epack, rp_dst, rp_src, col_dst, col_src, x, W1uh, W1ul, W1dh, W1dl,
        b_u1, b_d1, Yu, Yd);
    // layer 1
    gather2_kernel<<<2 * GBS, 256, 0, stream>>>(Yu, rp_dst, col_dst, agg_uh,
                                                agg_ul, Yd, rp_src, col_src,
                                                agg_dh, agg_dl);
    update2m_kernel<<<2 * TB, 256, 0, stream>>>(x, agg_uh, agg_ul, agg_dh,
                                                agg_dl, U1uh, U1ul, U1dh,
                                                U1dl, outh, outl);
    // round 2
    mgemm_kernel<<<TB, 256, 0, stream>>>(outh, outl, 128, nullptr, nullptr,
                                         W2uh, W2ul, 128, b_u2, Y2, nullptr,
                                         nullptr, 64, 0, 0, 2, 2);
    gather_kernel<<<GBS, 256, 0, stream>>>(Y2, rp_dst, col_dst, nullptr,
                                           agg2h, agg2l);
    mgemm_kernel<<<TB, 256, 0, stream>>>(outh, outl, 128, agg2h, agg2l,
                                         U2uh, U2ul, 192, nullptr, nullptr,
                                         O2h, O2l, 64, 0, 0, 3, 2);
    // round 3 (h = [O2,O2] folded into presummed weights)
    mgemm_kernel<<<TB, 256, 0, stream>>>(O2h, O2l, 64, nullptr, nullptr,
                                         Wsh, Wsl, 64, b_u2, Y2, nullptr,
                                         nullptr, 64, 0, 0, 1, 1);
    gather_kernel<<<GBS, 256, 0, stream>>>(Y2, rp_dst, col_dst, nullptr,
                                           agg2h, agg2l);
    mgemm_kernel<<<TB, 256, 0, stream>>>(O2h, O2l, 64, agg2h, agg2l,
                                         Ush, Usl, 128, nullptr, out,
                                         nullptr, nullptr, 128, 0, 1, 2, 1);
  } else {
    // fallback: vector-f32 path
    float* Y_u = (float*)wsb; wsb += (size_t)NN * 64 * sizeof(float);
    float* Y_d = (float*)wsb; wsb += (size_t)NN * 64 * sizeof(float);
    float* AGG = (float*)wsb;
    count_kernel<<<NP, 256, 0, stream>>>(epack, rp_dst, rp_src);
    scan_kernel<<<2, 1024, 0, stream>>>(rp_dst, rp_src);
    fused0_kernel<<<NP + 2 * TB, 256, 0, stream>>>(
        epack, rp_dst, rp_src, col_dst, col_src, x, W_u1, b_u1, Y_u, W_d1,
        b_d1, Y_d);
    gather_kernel<<<GBS, 256, 0, stream>>>(Y_u, rp_dst, col_dst, AGG,
                                           nullptr, nullptr);
    gemm_kernel<<<TB, 256, 0, stream>>>(x, 128, AGG, U_u1, nullptr, out,
                                        128, 0, 0, 3, 2);
    gather_kernel<<<GBS, 256, 0, stream>>>(Y_d, rp_src, col_src, AGG,
                                           nullptr, nullptr);
    gemm_kernel<<<TB, 256, 0, stream>>>(x, 128, AGG, U_d1, nullptr, out,
                                        128, 64, 0, 3, 2);
    for (int r = 0; r < 2; ++r) {
      gemm_kernel<<<TB, 256, 0, stream>>>(out, 128, nullptr, W_u2, b_u2,
                                          Y_u, 64, 0, 0, 2, 2);
      gather_kernel<<<GBS, 256, 0, stream>>>(Y_u, rp_dst, col_dst, AGG,
                                             nullptr, nullptr);
      gemm_kernel<<<TB, 256, 0, stream>>>(out, 128, AGG, U_u2, nullptr,
                                          out, 128, 0, 1, 3, 2);
    }
  }
}

// Round 8
// 402.106 us; speedup vs baseline: 7.3027x; 1.0016x over previous
//
#include <hip/hip_runtime.h>

#define NN 50000
#define NE 800000
#define NP 2048            // strided edge-work blocks (256 per XCD range)
#define TB 782             // ceil(NN/64) gemm row-tile blocks
#define GBS 12504          // 8 * 1563 swizzled gather blocks (4 nodes each)

typedef __attribute__((ext_vector_type(8))) short bhalf8;
typedef __attribute__((ext_vector_type(4))) float floatx4;

// weight buffer offsets (ushort units); l plane = h + 64*K
#define WOFF_U1U 0
#define WOFF_U1D 24576
#define WOFF_W1U 49152
#define WOFF_W1D 65536
#define WOFF_W2U 81920
#define WOFF_U2U 98304
#define WOFF_WSUM 122880
#define WOFF_USUM 131072
#define WBUF_USHORTS 147456

// ---------------------------------------------------------------------------
// bf16 split helpers (RNE)
// ---------------------------------------------------------------------------
__device__ __forceinline__ unsigned short bf16hi(float v) {
  union { float f; unsigned u; } c; c.f = v;
  return (unsigned short)((c.u + 0x7FFFu + ((c.u >> 16) & 1u)) >> 16);
}
__device__ __forceinline__ float bf16tof(unsigned short h) {
  union { unsigned u; float f; } c; c.u = ((unsigned)h) << 16;
  return c.f;
}
__device__ __forceinline__ void split1(float v, unsigned short& h,
                                       unsigned short& l) {
  h = bf16hi(v);
  l = bf16hi(v - bf16tof(h));
}
__device__ __forceinline__ void split4(const float4 v, ushort4& h, ushort4& l) {
  split1(v.x, h.x, l.x);
  split1(v.y, h.y, l.y);
  split1(v.z, h.z, l.z);
  split1(v.w, h.w, l.w);
}
__device__ __forceinline__ void split8(const float4 v0, const float4 v1,
                                       uint4& H, uint4& L) {
  unsigned short h0, l0, h1, l1;
  split1(v0.x, h0, l0); split1(v0.y, h1, l1);
  H.x = (unsigned)h0 | ((unsigned)h1 << 16);
  L.x = (unsigned)l0 | ((unsigned)l1 << 16);
  split1(v0.z, h0, l0); split1(v0.w, h1, l1);
  H.y = (unsigned)h0 | ((unsigned)h1 << 16);
  L.y = (unsigned)l0 | ((unsigned)l1 << 16);
  split1(v1.x, h0, l0); split1(v1.y, h1, l1);
  H.z = (unsigned)h0 | ((unsigned)h1 << 16);
  L.z = (unsigned)l0 | ((unsigned)l1 << 16);
  split1(v1.z, h0, l0); split1(v1.w, h1, l1);
  H.w = (unsigned)h0 | ((unsigned)h1 << 16);
  L.w = (unsigned)l0 | ((unsigned)l1 << 16);
}

// swizzled LDS byte address for bf16 tile [64 rows][64 k] (128B rows)
#define SWZ(row, inrow) (((row) << 7) + ((inrow) ^ (((row)&7) << 4)))

// ---------------------------------------------------------------------------
// MFMA split-bf16 GEMM (single B): out = relu([A|G] @ B^T (+bias))
// ---------------------------------------------------------------------------
template <bool AF32>
__device__ __forceinline__ void mfma_gemm_dev(
    unsigned short* tAh, unsigned short* tAl,
    unsigned short* tBh, unsigned short* tBl,
    const unsigned short* __restrict__ Ah, const unsigned short* __restrict__ Al,
    int lda,
    const unsigned short* __restrict__ Gh, const unsigned short* __restrict__ Gl,
    const unsigned short* __restrict__ Bh, const unsigned short* __restrict__ Bl,
    int ldb, const float* __restrict__ bias,
    float* __restrict__ outF, unsigned short* __restrict__ outH,
    unsigned short* __restrict__ outL,
    int ldo, int colbase, int dup, int kchunks, int xchunks,
    int row0, int tid) {
  const int lane = tid & 63;
  const int wm = tid >> 6;
  const int m = lane & 15;
  const int kg = lane >> 4;
  floatx4 acc[4];
#pragma unroll
  for (int i = 0; i < 4; ++i) acc[i] = (floatx4){0.f, 0.f, 0.f, 0.f};

  for (int c = 0; c < kchunks; ++c) {
#pragma unroll
    for (int q = tid; q < 512; q += 256) {
      const int row = q >> 3, slot = q & 7;
      int gr = row0 + row;
      gr = (gr > NN - 1) ? NN - 1 : gr;
      const int ad = SWZ(row, slot << 4);
      if (AF32 && c < xchunks) {
        const float* f = (const float*)Ah;
        const size_t go = (size_t)gr * lda + (c << 6) + slot * 8;
        const float4 v0 = *(const float4*)(f + go);
        const float4 v1 = *(const float4*)(f + go + 4);
        uint4 H, L;
        split8(v0, v1, H, L);
        *(uint4*)((char*)tAh + ad) = H;
        *(uint4*)((char*)tAl + ad) = L;
      } else {
        const unsigned short* sh;
        const unsigned short* sl;
        int ld, kc;
        if (c < xchunks) { sh = Ah; sl = Al; ld = lda; kc = c << 6; }
        else             { sh = Gh; sl = Gl; ld = 64;  kc = 0; }
        const size_t go = (size_t)gr * ld + kc + slot * 8;
        *(uint4*)((char*)tAh + ad) = *(const uint4*)(sh + go);
        *(uint4*)((char*)tAl + ad) = *(const uint4*)(sl + go);
      }
      const size_t gob = (size_t)row * ldb + (c << 6) + slot * 8;
      *(uint4*)((char*)tBh + ad) = *(const uint4*)(Bh + gob);
      *(uint4*)((char*)tBl + ad) = *(const uint4*)(Bl + gob);
    }
    __syncthreads();
#pragma unroll
    for (int ks = 0; ks < 2; ++ks) {
      const int inrow = (ks << 6) + (kg << 4);
      const int rA = (wm << 4) + m;
      const bhalf8 ah = *(const bhalf8*)((const char*)tAh + SWZ(rA, inrow));
      const bhalf8 al = *(const bhalf8*)((const char*)tAl + SWZ(rA, inrow));
#pragma unroll
      for (int nt = 0; nt < 4; ++nt) {
        const int rB = (nt << 4) + m;
        const bhalf8 bh = *(const bhalf8*)((const char*)tBh + SWZ(rB, inrow));
        const bhalf8 bl = *(const bhalf8*)((const char*)tBl + SWZ(rB, inrow));
        acc[nt] = __builtin_amdgcn_mfma_f32_16x16x32_bf16(ah, bh, acc[nt], 0, 0, 0);
        acc[nt] = __builtin_amdgcn_mfma_f32_16x16x32_bf16(ah, bl, acc[nt], 0, 0, 0);
        acc[nt] = __builtin_amdgcn_mfma_f32_16x16x32_bf16(al, bh, acc[nt], 0, 0, 0);
      }
    }
    __syncthreads();
  }
#pragma unroll
  for (int nt = 0; nt < 4; ++nt) {
    const int col = colbase + (nt << 4) + m;
    const float bv = bias ? bias[(nt << 4) + m] : 0.f;
#pragma unroll
    for (int r = 0; r < 4; ++r) {
      const int row = row0 + (wm << 4) + (kg << 2) + r;
      if (row < NN) {
        const float v = fmaxf(acc[nt][r] + bv, 0.f);
        if (outF) {
          outF[(size_t)row * ldo + col] = v;
          if (dup) outF[(size_t)row * ldo + col + 64] = v;
        }
        if (outH) {
          unsigned short h, l;
          split1(v, h, l);
          outH[(size_t)row * ldo + col] = h;
          outL[(size_t)row * ldo + col] = l;
        }
      }
    }
  }
}

// ---------------------------------------------------------------------------
// Dual-output transform, 4-tile (32KB) version: stage x chunk once, run W_u1
// B-tiles, resync, restage W_d1 into the SAME B-tiles.
// ---------------------------------------------------------------------------
__device__ __forceinline__ void trans2_dev(
    unsigned short* tAh, unsigned short* tAl,
    unsigned short* tBh, unsigned short* tBl,
    const float* __restrict__ x,
    const unsigned short* __restrict__ Wuh, const unsigned short* __restrict__ Wul,
    const unsigned short* __restrict__ Wdh, const unsigned short* __restrict__ Wdl,
    const float* __restrict__ bu, const float* __restrict__ bd,
    float* __restrict__ Yu, float* __restrict__ Yd, int row0, int tid) {
  const int lane = tid & 63;
  const int wm = tid >> 6;
  const int m = lane & 15;
  const int kg = lane >> 4;
  floatx4 accU[4], accD[4];
#pragma unroll
  for (int i = 0; i < 4; ++i) {
    accU[i] = (floatx4){0.f, 0.f, 0.f, 0.f};
    accD[i] = (floatx4){0.f, 0.f, 0.f, 0.f};
  }
  for (int c = 0; c < 2; ++c) {
    // stage A (x, split in-register) and B = W_u1 chunk
#pragma unroll
    for (int q = tid; q < 512; q += 256) {
      const int row = q >> 3, slot = q & 7;
      int gr = row0 + row;
      gr = (gr > NN - 1) ? NN - 1 : gr;
      const int ad = SWZ(row, slot << 4);
      const size_t go = (size_t)gr * 128 + (c << 6) + slot * 8;
      const float4 v0 = *(const float4*)(x + go);
      const float4 v1 = *(const float4*)(x + go + 4);
      uint4 H, L;
      split8(v0, v1, H, L);
      *(uint4*)((char*)tAh + ad) = H;
      *(uint4*)((char*)tAl + ad) = L;
      const size_t gob = (size_t)row * 128 + (c << 6) + slot * 8;
      *(uint4*)((char*)tBh + ad) = *(const uint4*)(Wuh + gob);
      *(uint4*)((char*)tBl + ad) = *(const uint4*)(Wul + gob);
    }
    __syncthreads();
#pragma unroll
    for (int ks = 0; ks < 2; ++ks) {
      const int inrow = (ks << 6) + (kg << 4);
      const int rA = (wm << 4) + m;
      const bhalf8 ah = *(const bhalf8*)((const char*)tAh + SWZ(rA, inrow));
      const bhalf8 al = *(const bhalf8*)((const char*)tAl + SWZ(rA, inrow));
#pragma unroll
      for (int nt = 0; nt < 4; ++nt) {
        const int rB = (nt << 4) + m;
        const int adB = SWZ(rB, inrow);
        const bhalf8 bh = *(const bhalf8*)((const char*)tBh + adB);
        const bhalf8 bl = *(const bhalf8*)((const char*)tBl + adB);
        accU[nt] = __builtin_amdgcn_mfma_f32_16x16x32_bf16(ah, bh, accU[nt], 0, 0, 0);
        accU[nt] = __builtin_amdgcn_mfma_f32_16x16x32_bf16(ah, bl, accU[nt], 0, 0, 0);
        accU[nt] = __builtin_amdgcn_mfma_f32_16x16x32_bf16(al, bh, accU[nt], 0, 0, 0);
      }
    }
    __syncthreads();
    // restage B = W_d1 chunk (A tile stays)
#pragma unroll
    for (int q = tid; q < 512; q += 256) {
      const int row = q >> 3, slot = q & 7;
      const int ad = SWZ(row, slot << 4);
      const size_t gob = (size_t)row * 128 + (c << 6) + slot * 8;
      *(uint4*)((char*)tBh + ad) = *(const uint4*)(Wdh + gob);
      *(uint4*)((char*)tBl + ad) = *(const uint4*)(Wdl + gob);
    }
    __syncthreads();
#pragma unroll
    for (int ks = 0; ks < 2; ++ks) {
      const int inrow = (ks << 6) + (kg << 4);
      const int rA = (wm << 4) + m;
      const bhalf8 ah = *(const bhalf8*)((const char*)tAh + SWZ(rA, inrow));
      const bhalf8 al = *(const bhalf8*)((const char*)tAl + SWZ(rA, inrow));
#pragma unroll
      for (int nt = 0; nt < 4; ++nt) {
        const int rB = (nt << 4) + m;
        const int adB = SWZ(rB, inrow);
        const bhalf8 bh = *(const bhalf8*)((const char*)tBh + adB);
        const bhalf8 bl = *(const bhalf8*)((const char*)tBl + adB);
        accD[nt] = __builtin_amdgcn_mfma_f32_16x16x32_bf16(ah, bh, accD[nt], 0, 0, 0);
        accD[nt] = __builtin_amdgcn_mfma_f32_16x16x32_bf16(ah, bl, accD[nt], 0, 0, 0);
        accD[nt] = __builtin_amdgcn_mfma_f32_16x16x32_bf16(al, bh, accD[nt], 0, 0, 0);
      }
    }
    __syncthreads();
  }
#pragma unroll
  for (int nt = 0; nt < 4; ++nt) {
    const int col = (nt << 4) + m;
    const float bvu = bu[col];
    const float bvd = bd[col];
#pragma unroll
    for (int r = 0; r < 4; ++r) {
      const int row = row0 + (wm << 4) + (kg << 2) + r;
      if (row < NN) {
        Yu[(size_t)row * 64 + col] = fmaxf(accU[nt][r] + bvu, 0.f);
        Yd[(size_t)row * 64 + col] = fmaxf(accD[nt][r] + bvd, 0.f);
      }
    }
  }
}

__global__ __launch_bounds__(256) void mgemm_kernel(
    const unsigned short* Ah, const unsigned short* Al, int lda,
    const unsigned short* Gh, const unsigned short* Gl,
    const unsigned short* Bh, const unsigned short* Bl, int ldb,
    const float* bias, float* outF, unsigned short* outH, unsigned short* outL,
    int ldo, int colbase, int dup, int kchunks, int xchunks) {
  __shared__ unsigned short tiles[4][4096];
  mfma_gemm_dev<false>(tiles[0], tiles[1], tiles[2], tiles[3], Ah, Al, lda,
                       Gh, Gl, Bh, Bl, ldb, bias, outF, outH, outL, ldo,
                       colbase, dup, kchunks, xchunks, blockIdx.x * 64,
                       threadIdx.x);
}

// both layer-1 updates in one launch; A = f32 x (inline split)
__global__ __launch_bounds__(256) void update2m_kernel(
    const float* __restrict__ x,
    const unsigned short* auh, const unsigned short* aul,
    const unsigned short* adh, const unsigned short* adl,
    const unsigned short* U1uh, const unsigned short* U1ul,
    const unsigned short* U1dh, const unsigned short* U1dl,
    unsigned short* outH, unsigned short* outL) {
  __shared__ unsigned short tiles[4][4096];
  if (blockIdx.x < TB)
    mfma_gemm_dev<true>(tiles[0], tiles[1], tiles[2], tiles[3],
                        (const unsigned short*)x, nullptr, 128, auh, aul,
                        U1uh, U1ul, 192, nullptr, nullptr, outH, outL, 128,
                        0, 0, 3, 2, blockIdx.x * 64, threadIdx.x);
  else
    mfma_gemm_dev<true>(tiles[0], tiles[1], tiles[2], tiles[3],
                        (const unsigned short*)x, nullptr, 128, adh, adl,
                        U1dh, U1dl, 192, nullptr, nullptr, outH, outL, 128,
                        64, 0, 3, 2, (blockIdx.x - TB) * 64, threadIdx.x);
}

// ---------------------------------------------------------------------------
// pack: (src,dst) int32 pairs -> u32 (s | d<<16)  [node ids < 65536]
// ---------------------------------------------------------------------------
__global__ __launch_bounds__(256) void pack_kernel(
    const int* __restrict__ src, const int* __restrict__ dst,
    unsigned* __restrict__ epack) {
  for (int e = blockIdx.x * 256 + threadIdx.x; e < NE; e += 1024 * 256)
    epack[e] = (unsigned)src[e] | ((unsigned)dst[e] << 16);
}

// ---------------------------------------------------------------------------
// 4-edge ILP count / place bodies (uint4 epack loads, independent atomics)
// thread g covers edges [g*4, g*4+4) stepping 262144 (= 65536 threads * 4)
// ---------------------------------------------------------------------------
__device__ __forceinline__ void count_dev4(
    const unsigned* __restrict__ epack,
    int* __restrict__ rp_dst, int* __restrict__ rp_src, int bi, int tid) {
  const unsigned lo = (unsigned)(bi & 7) * 6250u;
  const int g = (bi >> 3) * 256 + tid;
  for (int e = g * 4; e < NE; e += 262144) {
    const uint4 v4 = *(const uint4*)(epack + e);
    const unsigned vs[4] = {v4.x, v4.y, v4.z, v4.w};
#pragma unroll
    for (int i = 0; i < 4; ++i) {
      const unsigned s = vs[i] & 0xFFFFu, d = vs[i] >> 16;
      if (d - lo < 6250u) atomicAdd(&rp_dst[d], 1);
      if (s - lo < 6250u) atomicAdd(&rp_src[s], 1);
    }
  }
}

__device__ __forceinline__ void place_dev4(
    const unsigned* __restrict__ epack,
    int* __restrict__ rp_dst, int* __restrict__ rp_src,
    unsigned short* __restrict__ col_dst, unsigned short* __restrict__ col_src,
    int bi, int tid) {
  const unsigned lo = (unsigned)(bi & 7) * 6250u;
  const int g = (bi >> 3) * 256 + tid;
  for (int e = g * 4; e < NE; e += 262144) {
    const uint4 v4 = *(const uint4*)(epack + e);
    const unsigned vs[4] = {v4.x, v4.y, v4.z, v4.w};
#pragma unroll
    for (int i = 0; i < 4; ++i) {
      const unsigned s = vs[i] & 0xFFFFu, d = vs[i] >> 16;
      if (d - lo < 6250u)
        col_dst[atomicAdd(&rp_dst[d], 1)] = (unsigned short)s;
      if (s - lo < 6250u)
        col_src[atomicAdd(&rp_src[s], 1)] = (unsigned short)d;
    }
  }
}

// ---------------------------------------------------------------------------
// prep: XCD-partitioned ILP count (blocks [0,NP)) || weights (32 blocks)
// ---------------------------------------------------------------------------
__global__ __launch_bounds__(256) void prep_kernel(
    const unsigned* __restrict__ epack,
    int* __restrict__ rp_dst, int* __restrict__ rp_src,
    const float* __restrict__ U_u1, const float* __restrict__ U_d1,
    const float* __restrict__ W_u1, const float* __restrict__ W_d1,
    const float* __restrict__ W_u2, const float* __restrict__ U_u2,
    unsigned short* __restrict__ wbuf) {
  int bi = blockIdx.x;
  const int t = threadIdx.x;
  if (bi < NP) {
    count_dev4(epack, rp_dst, rp_src, bi, t);
    return;
  }
  bi -= NP;
  const int widx = bi >> 2;
  const int quad = bi & 3;
  const int Ks[8] = {192, 192, 128, 128, 128, 192, 64, 128};
  const int offs[8] = {WOFF_U1U, WOFF_U1D, WOFF_W1U, WOFF_W1D,
                       WOFF_W2U, WOFF_U2U, WOFF_WSUM, WOFF_USUM};
  const float* srcs[6] = {U_u1, U_d1, W_u1, W_d1, W_u2, U_u2};
  const int K = Ks[widx];
  const int off = offs[widx];
  const int qsz = K << 4;
  const int beg = quad * qsz;
  for (int e = beg + t; e < beg + qsz; e += 256) {
    const int cc = e / K;
    const int kk = e - cc * K;
    float v;
    if (widx < 6) v = srcs[widx][kk * 64 + cc];
    else if (widx == 6) v = W_u2[kk * 64 + cc] + W_u2[(kk + 64) * 64 + cc];
    else v = (kk < 64) ? (U_u2[kk * 64 + cc] + U_u2[(kk + 64) * 64 + cc])
                       : U_u2[(kk + 64) * 64 + cc];
    unsigned short h, l;
    split1(v, h, l);
    wbuf[off + cc * K + kk] = h;
    wbuf[off + (K << 6) + cc * K + kk] = l;
  }
}

// ---------------------------------------------------------------------------
// CSR scan (2 blocks)
// ---------------------------------------------------------------------------
#define CHUNK 49
__global__ __launch_bounds__(1024) void scan_kernel(
    int* __restrict__ a0, int* __restrict__ a1) {
  int* a = (blockIdx.x == 0) ? a0 : a1;
  __shared__ int part[1024];
  const int t = threadIdx.x;
  const int beg = t * CHUNK;
  const int end = min(beg + CHUNK, NN);
  int s = 0;
  for (int i = beg; i < end; ++i) s += a[i];
  part[t] = s;
  __syncthreads();
  for (int off = 1; off < 1024; off <<= 1) {
    int add = (t >= off) ? part[t - off] : 0;
    __syncthreads();
    part[t] += add;
    __syncthreads();
  }
  int run = (t == 0) ? 0 : part[t - 1];
  for (int i = beg; i < end; ++i) {
    const int c = a[i];
    a[i] = run;
    run += c;
  }
}

// ---------------------------------------------------------------------------
// fused1: ILP place (blocks [0,NP)) || dual-output transform (TB blocks)
// ---------------------------------------------------------------------------
__global__ __launch_bounds__(256) void fused1_kernel(
    const unsigned* __restrict__ epack,
    int* __restrict__ rp_dst, int* __restrict__ rp_src,
    unsigned short* __restrict__ col_dst, unsigned short* __restrict__ col_src,
    const float* __restrict__ x,
    const unsigned short* W1uh, const unsigned short* W1ul,
    const unsigned short* W1dh, const unsigned short* W1dl,
    const float* __restrict__ b_u1, const float* __restrict__ b_d1,
    float* __restrict__ Yu, float* __restrict__ Yd) {
  __shared__ unsigned short tiles[4][4096];
  int bi = blockIdx.x;
  if (bi < NP) {
    place_dev4(epack, rp_dst, rp_src, col_dst, col_src, bi, threadIdx.x);
    return;
  }
  bi -= NP;
  trans2_dev(tiles[0], tiles[1], tiles[2], tiles[3],
             x, W1uh, W1ul, W1dh, W1dl, b_u1, b_d1, Yu, Yd,
             bi * 64, threadIdx.x);
}

// ---------------------------------------------------------------------------
// pull-gather mean (u16 col), XCD-aligned node swizzle
// ---------------------------------------------------------------------------
__device__ __forceinline__ void gather_dev(
    const float* __restrict__ Y, const int* __restrict__ rowptr,
    const unsigned short* __restrict__ col, float* __restrict__ AGGf,
    unsigned short* __restrict__ aggh, unsigned short* __restrict__ aggl,
    int seg, int tid) {
  const int w = tid >> 6;
  const int lane = tid & 63;
  const int off = (seg >> 3) * 4 + w;
  if (off >= 6250) return;
  const int node = (seg & 7) * 6250 + off;
  const int eg = lane >> 4;
  const int cq = (lane & 15) << 2;
  const int start = (node == 0) ? 0 : rowptr[node - 1];
  const int end = rowptr[node];
  float4 acc = make_float4(0.f, 0.f, 0.f, 0.f);
  int e = start + eg;
  for (; e + 12 < end; e += 16) {
    const int j0 = col[e];
    const int j1 = col[e + 4];
    const int j2 = col[e + 8];
    const int j3 = col[e + 12];
    const float4 y0 = *(const float4*)(Y + j0 * 64 + cq);
    const float4 y1 = *(const float4*)(Y + j1 * 64 + cq);
    const float4 y2 = *(const float4*)(Y + j2 * 64 + cq);
    const float4 y3 = *(const float4*)(Y + j3 * 64 + cq);
    acc.x += y0.x + y1.x + y2.x + y3.x;
    acc.y += y0.y + y1.y + y2.y + y3.y;
    acc.z += y0.z + y1.z + y2.z + y3.z;
    acc.w += y0.w + y1.w + y2.w + y3.w;
  }
  for (; e < end; e += 4) {
    const float4 y = *(const float4*)(Y + col[e] * 64 + cq);
    acc.x += y.x; acc.y += y.y; acc.z += y.z; acc.w += y.w;
  }
  acc.x += __shfl_xor(acc.x, 16);
  acc.y += __shfl_xor(acc.y, 16);
  acc.z += __shfl_xor(acc.z, 16);
  acc.w += __shfl_xor(acc.w, 16);
  acc.x += __shfl_xor(acc.x, 32);
  acc.y += __shfl_xor(acc.y, 32);
  acc.z += __shfl_xor(acc.z, 32);
  acc.w += __shfl_xor(acc.w, 32);
  if (eg == 0) {
    const float inv = 1.f / (float)max(end - start, 1);
    float4 o;
    o.x = acc.x * inv; o.y = acc.y * inv;
    o.z = acc.z * inv; o.w = acc.w * inv;
    if (AGGf) {
      *(float4*)(AGGf + node * 64 + cq) = o;
    } else {
      ushort4 h, l;
      split4(o, h, l);
      *(ushort4*)(aggh + node * 64 + cq) = h;
      *(ushort4*)(aggl + node * 64 + cq) = l;
    }
  }
}

__global__ __launch_bounds__(256) void gather_kernel(
    const float* __restrict__ Y, const int* __restrict__ rowptr,
    const unsigned short* __restrict__ col, float* __restrict__ AGGf,
    unsigned short* __restrict__ aggh, unsigned short* __restrict__ aggl) {
  gather_dev(Y, rowptr, col, AGGf, aggh, aggl, blockIdx.x, threadIdx.x);
}

__global__ __launch_bounds__(256) void gather2_kernel(
    const float* __restrict__ Yu, const int* __restrict__ rp_dst,
    const unsigned short* __restrict__ col_dst,
    unsigned short* auh, unsigned short* aul,
    const float* __restrict__ Yd, const int* __restrict__ rp_src,
    const unsigned short* __restrict__ col_src,
    unsigned short* adh, unsigned short* adl) {
  if (blockIdx.x < GBS)
    gather_dev(Yu, rp_dst, col_dst, nullptr, auh, aul, blockIdx.x, threadIdx.x);
  else
    gather_dev(Yd, rp_src, col_src, nullptr, adh, adl, blockIdx.x - GBS,
               threadIdx.x);
}

// ===========================================================================
// Fallback path (vector-f32 GEMM) for small workspaces
// ===========================================================================
__device__ __forceinline__ void gemm64_dev(
    float (*Xt)[68], float* Ws, const float* __restrict__ X, int ldx,
    const float* __restrict__ AGG, const float* __restrict__ W,
    const float* __restrict__ b, float* __restrict__ out, int ldo,
    int colbase, int dup, int kchunks, int xchunks, int row0, int tid) {
  const int tx = tid & 15, ty = tid >> 4;
  float acc[4][4] = {{0.f}};
  for (int c = 0; c < kchunks; ++c) {
    {
      const int rr = tid >> 2;
      const int cg = (tid & 3) << 4;
      const float* srcp;
      int ld, co;
      if (c < xchunks) { srcp = X; ld = ldx; co = c * 64; }
      else             { srcp = AGG; ld = 64; co = 0; }
      int row = row0 + rr;
      if (row > NN - 1) row = NN - 1;
      const float* g = srcp + row * ld + co + cg;
      const float4 v0 = *(const float4*)(g + 0);
      const float4 v1 = *(const float4*)(g + 4);
      const float4 v2 = *(const float4*)(g + 8);
      const float4 v3 = *(const float4*)(g + 12);
      Xt[cg + 0][rr] = v0.x;  Xt[cg + 1][rr] = v0.y;
      Xt[cg + 2][rr] = v0.z;  Xt[cg + 3][rr] = v0.w;
      Xt[cg + 4][rr] = v1.x;  Xt[cg + 5][rr] = v1.y;
      Xt[cg + 6][rr] = v1.z;  Xt[cg + 7][rr] = v1.w;
      Xt[cg + 8][rr] = v2.x;  Xt[cg + 9][rr] = v2.y;
      Xt[cg + 10][rr] = v2.z; Xt[cg + 11][rr] = v2.w;
      Xt[cg + 12][rr] = v3.x; Xt[cg + 13][rr] = v3.y;
      Xt[cg + 14][rr] = v3.z; Xt[cg + 15][rr] = v3.w;
      const float4* wg = (const float4*)(W + c * 64 * 64);
      float4* wl = (float4*)Ws;
      wl[tid] = wg[tid];
      wl[tid + 256] = wg[tid + 256];
      wl[tid + 512] = wg[tid + 512];
      wl[tid + 768] = wg[tid + 768];
    }
    __syncthreads();
#pragma unroll 8
    for (int kk = 0; kk < 64; ++kk) {
      const float4 a = *(const float4*)&Xt[kk][tx << 2];
      const float4 w = *(const float4*)&Ws[kk * 64 + (ty << 2)];
      acc[0][0] += a.x * w.x; acc[0][1] += a.x * w.y;
      acc[0][2] += a.x * w.z; acc[0][3] += a.x * w.w;
      acc[1][0] += a.y * w.x; acc[1][1] += a.y * w.y;
      acc[1][2] += a.y * w.z; acc[1][3] += a.y * w.w;
      acc[2][0] += a.z * w.x; acc[2][1] += a.z * w.y;
      acc[2][2] += a.z * w.z; acc[2][3] += a.z * w.w;
      acc[3][0] += a.w * w.x; acc[3][1] += a.w * w.y;
      acc[3][2] += a.w * w.z; acc[3][3] += a.w * w.w;
    }
    __syncthreads();
  }
  float4 bv = make_float4(0.f, 0.f, 0.f, 0.f);
  if (b) bv = *(const float4*)(b + (ty << 2));
#pragma unroll
  for (int i = 0; i < 4; ++i) {
    const int row = row0 + (tx << 2) + i;
    if (row < NN) {
      float4 o;
      o.x = fmaxf(acc[i][0] + bv.x, 0.f);
      o.y = fmaxf(acc[i][1] + bv.y, 0.f);
      o.z = fmaxf(acc[i][2] + bv.z, 0.f);
      o.w = fmaxf(acc[i][3] + bv.w, 0.f);
      *(float4*)(out + row * ldo + colbase + (ty << 2)) = o;
      if (dup) *(float4*)(out + row * ldo + 64 + (ty << 2)) = o;
    }
  }
}

__global__ __launch_bounds__(256) void gemm_kernel(
    const float* __restrict__ X, int ldx, const float* __restrict__ AGG,
    const float* __restrict__ W, const float* __restrict__ b,
    float* __restrict__ out, int ldo, int colbase, int dup,
    int kchunks, int xchunks) {
  __shared__ __align__(16) float Xt[64][68];
  __shared__ __align__(16) float Ws[4096];
  gemm64_dev(Xt, Ws, X, ldx, AGG, W, b, out, ldo, colbase, dup, kchunks,
             xchunks, blockIdx.x * 64, threadIdx.x);
}

__global__ __launch_bounds__(256) void count_kernel(
    const unsigned* __restrict__ epack,
    int* __restrict__ rp_dst, int* __restrict__ rp_src) {
  count_dev4(epack, rp_dst, rp_src, blockIdx.x, threadIdx.x);
}

__global__ __launch_bounds__(256) void fused0_kernel(
    const unsigned* __restrict__ epack,
    int* __restrict__ rp_dst, int* __restrict__ rp_src,
    unsigned short* __restrict__ col_dst, unsigned short* __restrict__ col_src,
    const float* __restrict__ x,
    const float* __restrict__ W_u1, const float* __restrict__ b_u1,
    float* __restrict__ Y_u,
    const float* __restrict__ W_d1, const float* __restrict__ b_d1,
    float* __restrict__ Y_d) {
  __shared__ __align__(16) float Xt[64][68];
  __shared__ __align__(16) float Ws[4096];
  int bi = blockIdx.x;
  if (bi < NP) {
    place_dev4(epack, rp_dst, rp_src, col_dst, col_src, bi, threadIdx.x);
    return;
  }
  bi -= NP;
  if (bi < TB)
    gemm64_dev(Xt, Ws, x, 128, nullptr, W_u1, b_u1, Y_u, 64, 0, 0, 2, 2,
               bi * 64, threadIdx.x);
  else
    gemm64_dev(Xt, Ws, x, 128, nullptr, W_d1, b_d1, Y_d, 64, 0, 0, 2, 2,
               (bi - TB) * 64, threadIdx.x);
}

// ===========================================================================
extern "C" void kernel_launch(void* const* d_in, const int* in_sizes, int n_in,
                              void* d_out, int out_size, void* d_ws, size_t ws_size,
                              hipStream_t stream) {
  const float* x    = (const float*)d_in[0];
  const int*   ei   = (const int*)d_in[1];
  const float* W_u1 = (const float*)d_in[2];
  const float* b_u1 = (const float*)d_in[3];
  const float* U_u1 = (const float*)d_in[4];
  const float* W_d1 = (const float*)d_in[5];
  const float* b_d1 = (const float*)d_in[6];
  const float* U_d1 = (const float*)d_in[7];
  const float* W_u2 = (const float*)d_in[8];
  const float* b_u2 = (const float*)d_in[9];
  const float* U_u2 = (const float*)d_in[10];
  const int* src = ei;
  const int* dst = ei + NE;
  float* out = (float*)d_out;

  char* wsb = (char*)d_ws;
  int* rp_dst  = (int*)wsb;              wsb += NN * sizeof(int);
  int* rp_src  = (int*)wsb;              wsb += NN * sizeof(int);
  unsigned* epack = (unsigned*)wsb;      wsb += (size_t)NE * 4;
  unsigned short* col_dst = (unsigned short*)wsb; wsb += (size_t)NE * 2;
  unsigned short* col_src = (unsigned short*)wsb; wsb += (size_t)NE * 2;

  const size_t needM = (size_t)2 * NN * 4 + (size_t)NE * 8 +
                       (size_t)WBUF_USHORTS * 2 +
                       (size_t)NN * 64 * 4 * 2 +    // Yu, Yd
                       (size_t)NN * 64 * 2 * 4 +    // 4 agg bf16 planes
                       (size_t)NN * 64 * 2 * 2;     // O2h, O2l

  hipMemsetAsync(rp_dst, 0, 2 * NN * sizeof(int), stream);
  pack_kernel<<<1024, 256, 0, stream>>>(src, dst, epack);

  if (ws_size >= needM) {
    unsigned short* wbuf = (unsigned short*)wsb; wsb += (size_t)WBUF_USHORTS * 2;
    float* Yu = (float*)wsb;                     wsb += (size_t)NN * 64 * 4;
    float* Yd = (float*)wsb;                     wsb += (size_t)NN * 64 * 4;
    unsigned short* agg_uh = (unsigned short*)wsb; wsb += (size_t)NN * 64 * 2;
    unsigned short* agg_ul = (unsigned short*)wsb; wsb += (size_t)NN * 64 * 2;
    unsigned short* agg_dh = (unsigned short*)wsb; wsb += (size_t)NN * 64 * 2;
    unsigned short* agg_dl = (unsigned short*)wsb; wsb += (size_t)NN * 64 * 2;
    unsigned short* O2h = (unsigned short*)wsb;    wsb += (size_t)NN * 64 * 2;
    unsigned short* O2l = (unsigned short*)wsb;

    // aliases (sequential lifetime reuse)
    unsigned short* outh = (unsigned short*)Yu;  // [N][128] bf16 hi
    unsigned short* outl = (unsigned short*)Yd;  // [N][128] bf16 lo
    float* Y2 = (float*)agg_uh;                  // [N][64] f32 (spans uh+ul)
    unsigned short* agg2h = agg_dh;
    unsigned short* agg2l = agg_dl;

    const unsigned short* U1uh = wbuf + WOFF_U1U;
    const unsigned short* U1ul = wbuf + WOFF_U1U + 64 * 192;
    const unsigned short* U1dh = wbuf + WOFF_U1D;
    const unsigned short* U1dl = wbuf + WOFF_U1D + 64 * 192;
    const unsigned short* W1uh = wbuf + WOFF_W1U;
    const unsigned short* W1ul = wbuf + WOFF_W1U + 64 * 128;
    const unsigned short* W1dh = wbuf + WOFF_W1D;
    const unsigned short* W1dl = wbuf + WOFF_W1D + 64 * 128;
    const unsigned short* W2uh = wbuf + WOFF_W2U;
    const unsigned short* W2ul = wbuf + WOFF_W2U + 64 * 128;
    const unsigned short* U2uh = wbuf + WOFF_U2U;
    const unsigned short* U2ul = wbuf + WOFF_U2U + 64 * 192;
    const unsigned short* Wsh  = wbuf + WOFF_WSUM;
    const unsigned short* Wsl  = wbuf + WOFF_WSUM + 64 * 64;
    const unsigned short* Ush  = wbuf + WOFF_USUM;
    const unsigned short* Usl  = wbuf + WOFF_USUM + 64 * 128;

    prep_kernel<<<NP + 32, 256, 0, stream>>>(
        epack, rp_dst, rp_src, U_u1, U_d1, W_u1, W_d1, W_u2, U_u2, wbuf);
    scan_kernel<<<2, 1024, 0, stream>>>(rp_dst, rp_src);
    fused1_kernel<<<NP + TB, 256, 0, stream>>>(
        epack, rp_dst, rp_src, col_dst, col_src, x, W1uh, W1ul, W1dh, W1dl,
        b_u1, b_d1, Yu, Yd);
    // layer 1
    gather2_kernel<<<2 * GBS, 256, 0, stream>>>(Yu, rp_dst, col_dst, agg_uh,
                                                agg_ul, Yd, rp_src, col_src,
                                                agg_dh, agg_dl);
    update2m_kernel<<<2 * TB, 256, 0, stream>>>(x, agg_uh, agg_ul, agg_dh,
                                                agg_dl, U1uh, U1ul, U1dh,
                                                U1dl, outh, outl);
    // round 2
    mgemm_kernel<<<TB, 256, 0, stream>>>(outh, outl, 128, nullptr, nullptr,
                                         W2uh, W2ul, 128, b_u2, Y2, nullptr,
                                         nullptr, 64, 0, 0, 2, 2);
    gather_kernel<<<GBS, 256, 0, stream>>>(Y2, rp_dst, col_dst, nullptr,
                                           agg2h, agg2l);
    mgemm_kernel<<<TB, 256, 0, stream>>>(outh, outl, 128, agg2h, agg2l,
                                         U2uh, U2ul, 192, nullptr, nullptr,
                                         O2h, O2l, 64, 0, 0, 3, 2);
    // round 3 (h = [O2,O2] folded into presummed weights)
    mgemm_kernel<<<TB, 256, 0, stream>>>(O2h, O2l, 64, nullptr, nullptr,
                                         Wsh, Wsl, 64, b_u2, Y2, nullptr,
                                         nullptr, 64, 0, 0, 1, 1);
    gather_kernel<<<GBS, 256, 0, stream>>>(Y2, rp_dst, col_dst, nullptr,
                                           agg2h, agg2l);
    mgemm_kernel<<<TB, 256, 0, stream>>>(O2h, O2l, 64, agg2h, agg2l,
                                         Ush, Usl, 128, nullptr, out,
                                         nullptr, nullptr, 128, 0, 1, 2, 1);
  } else {
    // fallback: vector-f32 path
    float* Y_u = (float*)wsb; wsb += (size_t)NN * 64 * sizeof(float);
    float* Y_d = (float*)wsb; wsb += (size_t)NN * 64 * sizeof(float);
    float* AGG = (float*)wsb;
    count_kernel<<<NP, 256, 0, stream>>>(epack, rp_dst, rp_src);
    scan_kernel<<<2, 1024, 0, stream>>>(rp_dst, rp_src);
    fused0_kernel<<<NP + 2 * TB, 256, 0, stream>>>(
        epack, rp_dst, rp_src, col_dst, col_src, x, W_u1, b_u1, Y_u, W_d1,
        b_d1, Y_d);
    gather_kernel<<<GBS, 256, 0, stream>>>(Y_u, rp_dst, col_dst, AGG,
                                           nullptr, nullptr);
    gemm_kernel<<<TB, 256, 0, stream>>>(x, 128, AGG, U_u1, nullptr, out,
                                        128, 0, 0, 3, 2);
    gather_kernel<<<GBS, 256, 0, stream>>>(Y_d, rp_src, col_src, AGG,
                                           nullptr, nullptr);
    gemm_kernel<<<TB, 256, 0, stream>>>(x, 128, AGG, U_d1, nullptr, out,
                                        128, 64, 0, 3, 2);
    for (int r = 0; r < 2; ++r) {
      gemm_kernel<<<TB, 256, 0, stream>>>(out, 128, nullptr, W_u2, b_u2,
                                          Y_u, 64, 0, 0, 2, 2);
      gather_kernel<<<GBS, 256, 0, stream>>>(Y_u, rp_dst, col_dst, AGG,
                                             nullptr, nullptr);
      gemm_kernel<<<TB, 256, 0, stream>>>(out, 128, AGG, U_u2, nullptr,
                                          out, 128, 0, 1, 3, 2);
    }
  }
}